// Round 10
// baseline (316.302 us; speedup 1.0000x reference)
//
#include <hip/hip_runtime.h>
#include <cstddef>

#define NB 32
#define NN 2000
#define NRD 32
#define NE 128
#define NH 256
#define NA 8
#define KP8 2048         // conv K padded (fp8, BK=64)
#define NGP 128          // node-quad groups per batch in k_agent
#define ACTION_NORM 2000.0f

typedef unsigned short u16;
typedef unsigned char u8;
typedef __bf16 b16x8 __attribute__((ext_vector_type(8)));
typedef float f32x4 __attribute__((ext_vector_type(4)));
typedef long lx2 __attribute__((ext_vector_type(2)));
typedef const __attribute__((address_space(1))) unsigned int* gptr_t;
typedef __attribute__((address_space(3))) unsigned int* lptr_t;

__device__ inline u16 f2bf(float x) {
    unsigned u = __float_as_uint(x);
    u += 0x7FFFu + ((u >> 16) & 1u);
    return (u16)(u >> 16);
}
__device__ inline float bf2f(u16 h) { return __uint_as_float((unsigned)h << 16); }
__device__ inline u8 f2fp8(float x) {
    return (u8)(__builtin_amdgcn_cvt_pk_fp8_f32(x, x, 0, false) & 0xFF);
}
__device__ inline u16 f2fp8x2(float a, float b) {
    return (u16)(__builtin_amdgcn_cvt_pk_fp8_f32(a, b, 0, false) & 0xFFFF);
}
// fp8 K-swizzle: within each 64-byte k-block, group j = [8j..8j+8) ++ [32+8j..32+8j+8)
// so conv fragment reads are one lane-linear ds_read_b128 (conflict-free).
__device__ inline int kswz(int m) {
    return (m & ~63) + (((m >> 3) & 3) << 4) + (((m >> 5) & 1) << 3) + (m & 7);
}

// ---------------------------------------------------------------- front: prep + dm partial max + actions init
#define PREP_STATE (64000 * 32)
#define PREP_W1T   (256 * 32)
#define PREP_W2T   (128 * 256)
#define PREP_WQ1T  (256 * 128)
#define PREP_PAD   (4096 * 48)
#define PREP_TOT   (PREP_STATE + PREP_W1T + PREP_W2T + PREP_WQ1T + PREP_PAD)
#define PREP_BLOCKS (PREP_TOT / 256)       // 9056
#define MAX_BLOCKS 1024
__global__ __launch_bounds__(256) void k_front(
        const float* __restrict__ state, const float* __restrict__ W1,
        const float* __restrict__ W2, const float* __restrict__ Wq1,
        const float* __restrict__ dm, const int* __restrict__ fa,
        const int* __restrict__ fid,
        u16* __restrict__ state_b, u16* __restrict__ W1t,
        u16* __restrict__ W2t, u16* __restrict__ Wq1at,
        u8* __restrict__ encb, float* __restrict__ pmax,
        float* __restrict__ actions) {
    __shared__ float sh[256];
    const int blk = blockIdx.x, t = threadIdx.x;
    if (blk < PREP_BLOCKS) {
        int i = blk * 256 + t;
        if (i < PREP_STATE) { state_b[i] = f2bf(state[i]); return; }
        i -= PREP_STATE;
        if (i < PREP_W1T) { int h = i >> 5, k = i & 31; W1t[i] = f2bf(W1[k * NH + h]); return; }
        i -= PREP_W1T;
        if (i < PREP_W2T) { int e = i >> 8, h = i & 255; W2t[i] = f2bf(W2[h * NE + e]); return; }
        i -= PREP_W2T;
        if (i < PREP_WQ1T) { int hq = i >> 7, e = i & 127; Wq1at[i] = f2bf(Wq1[e * NH + hq]); return; }
        i -= PREP_WQ1T;
        if (i < PREP_PAD) { int eb = i / 48, mm = NN + (i % 48); encb[(size_t)eb * KP8 + kswz(mm)] = 0; }
        return;
    }
    if (blk < PREP_BLOCKS + MAX_BLOCKS) {
        const int bid = blk - PREP_BLOCKS;
        float m = 0.0f;
        for (size_t i = (size_t)bid * 256 + t; i < (size_t)NN * NN; i += (size_t)MAX_BLOCKS * 256)
            m = fmaxf(m, dm[i]);
        sh[t] = m; __syncthreads();
        for (int s = 128; s > 0; s >>= 1) {
            if (t < s) sh[t] = fmaxf(sh[t], sh[t + s]);
            __syncthreads();
        }
        if (t == 0) pmax[bid] = sh[0];
        return;
    }
    // init actions (t = b*8 + a)
    const int b = t >> 3, a = t & 7;
    float v = -1.0f;
    for (int j = 0; j < 3; ++j)
        if (fid[j] == a) v = (float)fa[j * NB + b] / ACTION_NORM;
    actions[t] = v;
}

// ---------------------------------------------------------------- merged: enc1 GEMM (blocks 0..999) + sim (blocks 1000..2999)
__global__ __launch_bounds__(256) void k_gemm1s(
        const u16* __restrict__ A, const u16* __restrict__ Bt, u16* __restrict__ C,
        const float* __restrict__ bias,
        const float* __restrict__ dm, const float* __restrict__ pmax,
        u8* __restrict__ simb, float* __restrict__ inv_rs) {
    __shared__ u16 lds[16 * 512];
    const int blk = blockIdx.x, tid = threadIdx.x;

    if (blk >= 1000) {
        // ---------------- sim part
        float* shf = (float*)lds;
        const int n = blk - 1000, t = tid;
        float m = fmaxf(fmaxf(pmax[t], pmax[t + 256]), fmaxf(pmax[t + 512], pmax[t + 768]));
        shf[t] = m; __syncthreads();
        for (int s = 128; s > 0; s >>= 1) {
            if (t < s) shf[t] = fmaxf(shf[t], shf[t + s]);
            __syncthreads();
        }
        const float inv = 1.0f / shf[0];
        __syncthreads();
        float s = 0.0f;
        for (int mm = t * 2; mm < KP8; mm += 512) {
            float e0 = 0.0f, e1 = 0.0f;
            if (mm < NN)     { e0 = expf(-dm[(size_t)n * NN + mm] * inv);     s += e0; }
            if (mm + 1 < NN) { e1 = expf(-dm[(size_t)n * NN + mm + 1] * inv); s += e1; }
            *(u16*)(simb + (size_t)n * KP8 + kswz(mm)) = f2fp8x2(e0, e1);
        }
        shf[t] = s; __syncthreads();
        for (int st = 128; st > 0; st >>= 1) {
            if (t < st) shf[t] += shf[t + st];
            __syncthreads();
        }
        if (t == 0) inv_rs[n] = 1.0f / shf[0];
        return;
    }

    // ---------------- enc1 GEMM part (flattened (500,2) grid)
    const int w = tid >> 6, l = tid & 63;
    const int wr = w & 1, wc = w >> 1;
    const int bm = (blk >> 1) * 128, bn = (blk & 1) * 128;
    const int lm = l & 15, lq = l >> 4;

    f32x4 acc[4][4] = {};
    {
        __syncthreads();
#pragma unroll
        for (int i = 0; i < 4; ++i) {
            const int idx = w * 4 + i;
            const u16* gp;
            if (idx < 8) {
                gp = A + (size_t)(bm + idx * 16 + lm) * NRD + lq * 8;
            } else {
                gp = Bt + (size_t)(bn + (idx - 8) * 16 + lm) * NRD + lq * 8;
            }
            __builtin_amdgcn_global_load_lds((gptr_t)gp, (lptr_t)(lds + idx * 512), 16, 0, 0);
        }
        __syncthreads();
        b16x8 af[4], bf[4];
#pragma unroll
        for (int i = 0; i < 4; ++i) {
            af[i] = *(const b16x8*)(lds + (wr * 4 + i) * 512 + l * 8);
            bf[i] = *(const b16x8*)(lds + (8 + wc * 4 + i) * 512 + l * 8);
        }
#pragma unroll
        for (int fr = 0; fr < 4; ++fr)
#pragma unroll
            for (int fc = 0; fc < 4; ++fc)
                acc[fr][fc] = __builtin_amdgcn_mfma_f32_16x16x32_bf16(af[fr], bf[fc], acc[fr][fc], 0, 0, 0);
    }
#pragma unroll
    for (int fr = 0; fr < 4; ++fr) {
#pragma unroll
        for (int r = 0; r < 4; ++r) {
            const int row = bm + wr * 64 + fr * 16 + lq * 4 + r;
#pragma unroll
            for (int fc = 0; fc < 4; ++fc) {
                const int col = bn + wc * 64 + fc * 16 + lm;
                const float v = fmaxf(acc[fr][fc][r] + bias[col], 0.0f);
                C[(size_t)row * NH + col] = f2bf(v);
            }
        }
    }
}

// ---------------------------------------------------------------- enc2: 512 threads, bf16 in, fp8 PERM+kswz out
__global__ __launch_bounds__(512) void k_enc2(
        const u16* __restrict__ W2t, const u16* __restrict__ h1,
        u8* __restrict__ encb, const float* __restrict__ b2) {
    __shared__ u16 lds[16 * 512];
    const int tid = threadIdx.x;
    const int w = tid >> 6, l = tid & 63;   // 8 waves
    const int wr = w & 1, wc = w >> 1;      // wc in [0,4)
    const int bn = blockIdx.y * 128;
    const int lm = l & 15, lq = l >> 4;

    f32x4 acc[4][2] = {};

    for (int k0 = 0; k0 < NH; k0 += 32) {
        __syncthreads();
#pragma unroll
        for (int i = 0; i < 2; ++i) {
            const int idx = w * 2 + i;
            const u16* gp;
            if (idx < 8) {
                gp = W2t + (size_t)(idx * 16 + lm) * NH + k0 + lq * 8;
            } else {
                gp = h1 + (size_t)(bn + (idx - 8) * 16 + lm) * NH + k0 + lq * 8;
            }
            __builtin_amdgcn_global_load_lds((gptr_t)gp, (lptr_t)(lds + idx * 512), 16, 0, 0);
        }
        __syncthreads();
        b16x8 af[4], bf[2];
#pragma unroll
        for (int i = 0; i < 4; ++i) af[i] = *(const b16x8*)(lds + (wr * 4 + i) * 512 + l * 8);
#pragma unroll
        for (int j = 0; j < 2; ++j) bf[j] = *(const b16x8*)(lds + (8 + wc * 2 + j) * 512 + l * 8);
#pragma unroll
        for (int i = 0; i < 4; ++i)
#pragma unroll
            for (int j = 0; j < 2; ++j)
                acc[i][j] = __builtin_amdgcn_mfma_f32_16x16x32_bf16(af[i], bf[j], acc[i][j], 0, 0, 0);
    }

#pragma unroll
    for (int i = 0; i < 4; ++i) {
#pragma unroll
        for (int r = 0; r < 4; ++r) {
            const int row = wr * 64 + i * 16 + lq * 4 + r;   // 0..127
            const float bias = b2[row];
#pragma unroll
            for (int j = 0; j < 2; ++j) {
                const int col = bn + wc * 32 + j * 16 + lm;
                const unsigned bb = (unsigned)col / 2000u;
                const unsigned mm = (unsigned)col - bb * 2000u;
                encb[((size_t)bb * 128 + row) * KP8 + kswz((int)mm)] = f2fp8(acc[i][j][r] + bias);
            }
        }
    }
}

// ---------------------------------------------------------------- conv GEMM fp8, 128x128 tile, BK=64, 512 threads
// Xt[n][(b,e)] = inv_rs[n] * (simb8 @ encb8^T), bf16 out. kswz layout -> b128 frag reads.
__global__ __launch_bounds__(512) void k_conv(
        const u8* __restrict__ simb, const u8* __restrict__ encb,
        u16* __restrict__ Xt, const float* __restrict__ inv_rs) {
    __shared__ u8 lds[16 * 1024];           // 16 chunks x 1KB (A: 0-7, B: 8-15)
    const int tid = threadIdx.x;
    const int w = tid >> 6, l = tid & 63;   // 8 waves
    const int wr = w & 1, wc = w >> 1;      // wc in [0,4)
    const int bm = blockIdx.x * 128, bn = blockIdx.y * 128;
    const int lm = l & 15, lq = l >> 4;

    f32x4 acc[4][2] = {};

    for (int k0 = 0; k0 < KP8; k0 += 64) {
        __syncthreads();
#pragma unroll
        for (int i = 0; i < 2; ++i) {
            const int idx = w * 2 + i;
            const u8* gp;
            if (idx < 8) {
                int row = bm + idx * 16 + lm;
                row = row < NN ? row : NN - 1;
                gp = simb + (size_t)row * KP8 + k0 + lq * 16;
            } else {
                gp = encb + (size_t)(bn + (idx - 8) * 16 + lm) * KP8 + k0 + lq * 16;
            }
            __builtin_amdgcn_global_load_lds((gptr_t)gp, (lptr_t)(lds + idx * 1024), 16, 0, 0);
        }
        __syncthreads();
        const int fo = l * 16;              // lane-linear b128: conflict-free
        lx2 af[4], bf[2];
#pragma unroll
        for (int i = 0; i < 4; ++i)
            af[i] = *(const lx2*)(lds + (wr * 4 + i) * 1024 + fo);
#pragma unroll
        for (int j = 0; j < 2; ++j)
            bf[j] = *(const lx2*)(lds + (8 + wc * 2 + j) * 1024 + fo);
#pragma unroll
        for (int i = 0; i < 4; ++i)
#pragma unroll
            for (int j = 0; j < 2; ++j) {
                acc[i][j] = __builtin_amdgcn_mfma_f32_16x16x32_fp8_fp8(af[i][0], bf[j][0], acc[i][j], 0, 0, 0);
                acc[i][j] = __builtin_amdgcn_mfma_f32_16x16x32_fp8_fp8(af[i][1], bf[j][1], acc[i][j], 0, 0, 0);
            }
    }

#pragma unroll
    for (int i = 0; i < 4; ++i) {
#pragma unroll
        for (int r = 0; r < 4; ++r) {
            const int row = bm + wr * 64 + i * 16 + lq * 4 + r;
            if (row >= NN) continue;
            const float rsv = inv_rs[row];
#pragma unroll
            for (int j = 0; j < 2; ++j) {
                const int col = bn + wc * 32 + j * 16 + lm;
                Xt[(size_t)row * 4096 + col] = f2bf(acc[i][j][r] * rsv);
            }
        }
    }
}

// ---------------------------------------------------------------- y0 GEMM: fp8-only store
__global__ __launch_bounds__(256) void k_y0(
        const u16* __restrict__ A, const u16* __restrict__ Bt,
        u8* __restrict__ Cf8, const float* __restrict__ bias) {
    __shared__ u16 lds[16 * 512];
    const int tid = threadIdx.x;
    const int w = tid >> 6, l = tid & 63;
    const int wr = w & 1, wc = w >> 1;
    const int bm = blockIdx.x * 128, bn = blockIdx.y * 128;
    const int lm = l & 15, lq = l >> 4;

    f32x4 acc[4][4] = {};

    for (int k0 = 0; k0 < NE; k0 += 32) {
        __syncthreads();
#pragma unroll
        for (int i = 0; i < 4; ++i) {
            const int idx = w * 4 + i;
            const u16* gp;
            if (idx < 8) {
                gp = A + (size_t)(bm + idx * 16 + lm) * NE + k0 + lq * 8;
            } else {
                gp = Bt + (size_t)(bn + (idx - 8) * 16 + lm) * NE + k0 + lq * 8;
            }
            __builtin_amdgcn_global_load_lds((gptr_t)gp, (lptr_t)(lds + idx * 512), 16, 0, 0);
        }
        __syncthreads();
        b16x8 af[4], bf[4];
#pragma unroll
        for (int i = 0; i < 4; ++i) {
            af[i] = *(const b16x8*)(lds + (wr * 4 + i) * 512 + l * 8);
            bf[i] = *(const b16x8*)(lds + (8 + wc * 4 + i) * 512 + l * 8);
        }
#pragma unroll
        for (int fr = 0; fr < 4; ++fr)
#pragma unroll
            for (int fc = 0; fc < 4; ++fc)
                acc[fr][fc] = __builtin_amdgcn_mfma_f32_16x16x32_bf16(af[fr], bf[fc], acc[fr][fc], 0, 0, 0);
    }

#pragma unroll
    for (int fr = 0; fr < 4; ++fr) {
#pragma unroll
        for (int r = 0; r < 4; ++r) {
            const int row = bm + wr * 64 + fr * 16 + lq * 4 + r;
#pragma unroll
            for (int fc = 0; fc < 4; ++fc) {
                const int col = bn + wc * 64 + fc * 16 + lm;
                Cf8[(size_t)row * NH + col] = f2fp8(acc[fr][fc][r] + bias[col]);
            }
        }
    }
}

// ---------------------------------------------------------------- per-agent kernel
// Phase A on fp8 y0 (quarter-wave per node); finalize recomputes y0 row at nsel
// from bf16 Xt x fp32 Wq1 (higher precision than a stored bf16 y0).
__global__ __launch_bounds__(256) void k_agent(
        const u8* __restrict__ y0f8, const u16* __restrict__ Xt,
        const float* __restrict__ Wq1, const float* __restrict__ Wq2,
        const float* __restrict__ bq1, const float* __restrict__ bq2,
        float* actions, const float2* __restrict__ pin, float2* __restrict__ pout,
        float* __restrict__ out, int ag) {
    __shared__ float sh[256];
    __shared__ float xrow[128];
    __shared__ float s_sam;
    const int t = threadIdx.x;
    const int lane = t & 63, wave = t >> 6;
    const int wg = blockIdx.x * 4 + wave;
    const int b = wg & 31, ng = wg >> 5;        // ng in [0,128)
    const int hl = lane & 15, qtr = lane >> 4;

    float act[NA];
#pragma unroll
    for (int a = 0; a < NA; ++a) act[a] = actions[b * NA + a];
    if (ag > 0) {
        const float2 p0 = pin[b * NGP + lane];
        const float2 p1 = pin[b * NGP + 64 + lane];
        float se0 = p0.x + p1.x, sn0 = p0.y + p1.y;
#pragma unroll
        for (int m = 32; m > 0; m >>= 1) {
            se0 += __shfl_xor(se0, m); sn0 += __shfl_xor(sn0, m);
        }
        const float sam = fminf(fmaxf(sn0 / se0, 0.0f), 2000.0f);
        act[ag - 1] = sam * (1.0f / ACTION_NORM);
    }
    // ap and w2 slices: h = hl*16 + 0..15
    float ap16[16] = {};
#pragma unroll
    for (int a = 0; a < NA; ++a) {
        const float av = act[a];
        const float4* wq = (const float4*)(Wq1 + (size_t)(NE + a) * NH + hl * 16);
#pragma unroll
        for (int jj = 0; jj < 4; ++jj) {
            const float4 w4 = wq[jj];
            ap16[jj * 4 + 0] = fmaf(av, w4.x, ap16[jj * 4 + 0]);
            ap16[jj * 4 + 1] = fmaf(av, w4.y, ap16[jj * 4 + 1]);
            ap16[jj * 4 + 2] = fmaf(av, w4.z, ap16[jj * 4 + 2]);
            ap16[jj * 4 + 3] = fmaf(av, w4.w, ap16[jj * 4 + 3]);
        }
    }
    float w2v[16];
    {
        const float4* w2p = (const float4*)(Wq2 + hl * 16);
#pragma unroll
        for (int jj = 0; jj < 4; ++jj) {
            const float4 w4 = w2p[jj];
            w2v[jj * 4 + 0] = w4.x; w2v[jj * 4 + 1] = w4.y;
            w2v[jj * 4 + 2] = w4.z; w2v[jj * 4 + 3] = w4.w;
        }
    }

    float se = 0.0f, sn = 0.0f;
#pragma unroll
    for (int k = 0; k < 4; ++k) {
        const int p = ng + k * NGP;
        if (p >= NN / 4) break;
        const int n = 4 * p + qtr;
        const uint4 yv = *(const uint4*)(y0f8 + (((size_t)n * NB + b) << 8) + hl * 16);
        const unsigned dw[4] = {yv.x, yv.y, yv.z, yv.w};
        float q = 0.0f;
#pragma unroll
        for (int d = 0; d < 4; ++d) {
            const auto lo = __builtin_amdgcn_cvt_pk_f32_fp8(dw[d], false);
            const auto hi = __builtin_amdgcn_cvt_pk_f32_fp8(dw[d], true);
            q += fmaxf(lo[0] + ap16[d * 4 + 0], 0.f) * w2v[d * 4 + 0];
            q += fmaxf(lo[1] + ap16[d * 4 + 1], 0.f) * w2v[d * 4 + 1];
            q += fmaxf(hi[0] + ap16[d * 4 + 2], 0.f) * w2v[d * 4 + 2];
            q += fmaxf(hi[1] + ap16[d * 4 + 3], 0.f) * w2v[d * 4 + 3];
        }
#pragma unroll
        for (int off = 1; off < 16; off <<= 1) q += __shfl_xor(q, off);
        const float e = expf(fminf(q, 60.0f));
        se += e; sn += e * (float)n;
    }
    se += __shfl_xor(se, 16); sn += __shfl_xor(sn, 16);
    se += __shfl_xor(se, 32); sn += __shfl_xor(sn, 32);
    if (lane == 0) pout[b * NGP + ng] = make_float2(se, sn);

    if (ag > 0 && blockIdx.x < NB) {
        const int bb = blockIdx.x;
        if (wave == 0) {
            const float2 p0 = pin[bb * NGP + lane];
            const float2 p1 = pin[bb * NGP + 64 + lane];
            float a1 = p0.x + p1.x, a2 = p0.y + p1.y;
#pragma unroll
            for (int m = 32; m > 0; m >>= 1) {
                a1 += __shfl_xor(a1, m); a2 += __shfl_xor(a2, m);
            }
            if (lane == 0) s_sam = fminf(fmaxf(a2 / a1, 0.0f), 2000.0f);
        }
        __syncthreads();
        const float sam = s_sam;
        const float samn = sam * (1.0f / ACTION_NORM);
        int nsel = (int)sam; if (nsel > NN - 1) nsel = NN - 1;
        if (t < 128) xrow[t] = bf2f(Xt[(size_t)nsel * 4096 + bb * 128 + t]);
        __syncthreads();
        float apt = 0.0f;
#pragma unroll
        for (int a = 0; a < NA; ++a) {
            const float av = (a == ag - 1) ? samn : actions[bb * NA + a];
            apt = fmaf(av, Wq1[(size_t)(NE + a) * NH + t], apt);
        }
        float y0v = bq1[t];
#pragma unroll 4
        for (int e = 0; e < NE; ++e)
            y0v = fmaf(xrow[e], Wq1[(size_t)e * NH + t], y0v);
        sh[t] = fmaxf(y0v + apt, 0.0f) * Wq2[t];
        __syncthreads();
        for (int s = 128; s > 0; s >>= 1) {
            if (t < s) sh[t] += sh[t + s];
            __syncthreads();
        }
        if (t == 0) {
            out[bb * NA + (ag - 1)] = sh[0] + bq2[0];
            actions[bb * NA + (ag - 1)] = samn;
        }
    }
}

// ---------------------------------------------------------------- tail: finalize agent 7 + chosen
__global__ __launch_bounds__(256) void k_fin(
        const u16* __restrict__ Xt, const float* __restrict__ Wq1,
        const float* __restrict__ Wq2, const float* __restrict__ bq1,
        const float* __restrict__ bq2, const float* __restrict__ actions,
        const float2* __restrict__ pin, float* __restrict__ out) {
    __shared__ float sh[256];
    __shared__ float xrow[128];
    __shared__ float s_sam;
    const int bb = blockIdx.x, t = threadIdx.x;
    const int lane = t & 63, wave = t >> 6;
    if (wave == 0) {
        const float2 p0 = pin[bb * NGP + lane];
        const float2 p1 = pin[bb * NGP + 64 + lane];
        float a1 = p0.x + p1.x, a2 = p0.y + p1.y;
#pragma unroll
        for (int m = 32; m > 0; m >>= 1) {
            a1 += __shfl_xor(a1, m); a2 += __shfl_xor(a2, m);
        }
        if (lane == 0) s_sam = fminf(fmaxf(a2 / a1, 0.0f), 2000.0f);
    }
    __syncthreads();
    const float sam = s_sam;
    const float samn = sam * (1.0f / ACTION_NORM);
    int nsel = (int)sam; if (nsel > NN - 1) nsel = NN - 1;
    if (t < 128) xrow[t] = bf2f(Xt[(size_t)nsel * 4096 + bb * 128 + t]);
    __syncthreads();
    float apt = 0.0f;
#pragma unroll
    for (int a = 0; a < NA; ++a) {
        const float av = (a == NA - 1) ? samn : actions[bb * NA + a];
        apt = fmaf(av, Wq1[(size_t)(NE + a) * NH + t], apt);
    }
    float y0v = bq1[t];
#pragma unroll 4
    for (int e = 0; e < NE; ++e)
        y0v = fmaf(xrow[e], Wq1[(size_t)e * NH + t], y0v);
    sh[t] = fmaxf(y0v + apt, 0.0f) * Wq2[t];
    __syncthreads();
    for (int s = 128; s > 0; s >>= 1) {
        if (t < s) sh[t] += sh[t + s];
        __syncthreads();
    }
    if (t == 0) out[bb * NA + (NA - 1)] = sh[0] + bq2[0];
    if (t < NA) {
        const float av = (t == NA - 1) ? samn : actions[bb * NA + t];
        out[NB * NA + bb * NA + t] = (float)(int)(av * ACTION_NORM);
    }
}

// ---------------------------------------------------------------- launch
extern "C" void kernel_launch(void* const* d_in, const int* in_sizes, int n_in,
                              void* d_out, int out_size, void* d_ws, size_t ws_size,
                              hipStream_t stream) {
    const float* state = (const float*)d_in[0];
    const float* dm    = (const float*)d_in[1];
    const float* W1    = (const float*)d_in[2];
    const float* b1    = (const float*)d_in[3];
    const float* W2    = (const float*)d_in[4];
    const float* b2    = (const float*)d_in[5];
    const float* Wq1   = (const float*)d_in[6];
    const float* bq1   = (const float*)d_in[7];
    const float* Wq2   = (const float*)d_in[8];
    const float* bq2   = (const float*)d_in[9];
    const int* fa      = (const int*)d_in[10];
    const int* fid     = (const int*)d_in[11];
    float* out = (float*)d_out;

    char* p = (char*)d_ws;
    u8* simb       = (u8*)p;       p += (size_t)NN * KP8;           // 4.10 MB
    u8* encb       = (u8*)p;       p += (size_t)4096 * KP8;         // 8.39 MB
    float* inv_rs  = (float*)p;    p += 2048 * 4;
    float* pmax    = (float*)p;    p += 1024 * 4;
    float* actions = (float*)p;    p += 256 * 4;
    float2* part0  = (float2*)p;   p += (size_t)NB * NGP * 8;
    float2* part1  = (float2*)p;   p += (size_t)NB * NGP * 8;
    u16* state_b   = (u16*)p;      p += (size_t)2048000 * 2;
    u16* W1t       = (u16*)p;      p += 8192 * 2;
    u16* W2t       = (u16*)p;      p += 32768 * 2;
    u16* Wq1at     = (u16*)p;      p += 32768 * 2;
    u16* h1        = (u16*)p;      p += (size_t)16384000 * 2;       // 32.8 MB
    u16* Xt        = (u16*)p;      p += (size_t)8192000 * 2;        // 16.4 MB
    u8* y0f8       = (u8*)p;       p += (size_t)16384000;           // 16.4 MB

    const int RTOT = NB * NN;  // 64000

    k_front<<<PREP_BLOCKS + MAX_BLOCKS + 1, 256, 0, stream>>>(
        state, W1, W2, Wq1, dm, fa, fid,
        state_b, W1t, W2t, Wq1at, encb, pmax, actions);
    k_gemm1s<<<3000, 256, 0, stream>>>(state_b, W1t, h1, b1, dm, pmax, simb, inv_rs);
    k_enc2<<<dim3(1, RTOT / 128), 512, 0, stream>>>(W2t, h1, encb, b2);
    k_conv<<<dim3(16, 32), 512, 0, stream>>>(simb, encb, Xt, inv_rs);
    k_y0<<<dim3(RTOT / 128, NH / 128), 256, 0, stream>>>(Xt, Wq1at, y0f8, bq1);

    for (int ag = 0; ag < NA; ++ag) {
        const float2* pin  = (ag & 1) ? part0 : part1;
        float2*       pout = (ag & 1) ? part1 : part0;
        k_agent<<<1024, 256, 0, stream>>>(y0f8, Xt, Wq1, Wq2, bq1, bq2, actions,
                                          pin, pout, out, ag);
    }
    k_fin<<<NB, 256, 0, stream>>>(Xt, Wq1, Wq2, bq1, bq2, actions, part1, out);
}

// Round 11
// 284.149 us; speedup vs baseline: 1.1132x; 1.1132x over previous
//
#include <hip/hip_runtime.h>
#include <cstddef>

#define NB 32
#define NN 2000
#define NRD 32
#define NE 128
#define NH 256
#define NA 8
#define KP8 2048         // conv K padded (fp8, BK=64)
#define NGP 128          // node-quad groups per batch in k_agent
#define H1S 264          // h1 LDS tile stride (u16): 16B-aligned, <=2-way banks
#define ACTION_NORM 2000.0f

typedef unsigned short u16;
typedef unsigned char u8;
typedef __bf16 b16x8 __attribute__((ext_vector_type(8)));
typedef float f32x4 __attribute__((ext_vector_type(4)));
typedef long lx2 __attribute__((ext_vector_type(2)));
typedef const __attribute__((address_space(1))) unsigned int* gptr_t;
typedef __attribute__((address_space(3))) unsigned int* lptr_t;

__device__ inline u16 f2bf(float x) {
    unsigned u = __float_as_uint(x);
    u += 0x7FFFu + ((u >> 16) & 1u);
    return (u16)(u >> 16);
}
__device__ inline float bf2f(u16 h) { return __uint_as_float((unsigned)h << 16); }
__device__ inline u8 f2fp8(float x) {
    return (u8)(__builtin_amdgcn_cvt_pk_fp8_f32(x, x, 0, false) & 0xFF);
}
__device__ inline u16 f2fp8x2(float a, float b) {
    return (u16)(__builtin_amdgcn_cvt_pk_fp8_f32(a, b, 0, false) & 0xFFFF);
}
// fp8 K-swizzle: within each 64-byte k-block, group j = [8j..8j+8) ++ [32+8j..32+8j+8)
// so conv fragment reads are one lane-linear ds_read_b128 (conflict-free; round-10 verified).
__device__ inline int kswz(int m) {
    return (m & ~63) + (((m >> 3) & 3) << 4) + (((m >> 5) & 1) << 3) + (m & 7);
}

// ---------------------------------------------------------------- front: prep + dm partial max + actions init
#define PREP_STATE (64000 * 32)
#define PREP_W1T   (256 * 32)
#define PREP_W2T   (128 * 256)
#define PREP_WQ1T  (256 * 128)
#define PREP_PAD   (4096 * 48)
#define PREP_TOT   (PREP_STATE + PREP_W1T + PREP_W2T + PREP_WQ1T + PREP_PAD)
#define PREP_BLOCKS (PREP_TOT / 256)       // 9056
#define MAX_BLOCKS 1024
__global__ __launch_bounds__(256) void k_front(
        const float* __restrict__ state, const float* __restrict__ W1,
        const float* __restrict__ W2, const float* __restrict__ Wq1,
        const float* __restrict__ dm, const int* __restrict__ fa,
        const int* __restrict__ fid,
        u16* __restrict__ state_b, u16* __restrict__ W1t,
        u16* __restrict__ W2t, u16* __restrict__ Wq1at,
        u8* __restrict__ encb, float* __restrict__ pmax,
        float* __restrict__ actions) {
    __shared__ float sh[256];
    const int blk = blockIdx.x, t = threadIdx.x;
    if (blk < PREP_BLOCKS) {
        int i = blk * 256 + t;
        if (i < PREP_STATE) { state_b[i] = f2bf(state[i]); return; }
        i -= PREP_STATE;
        if (i < PREP_W1T) { int h = i >> 5, k = i & 31; W1t[i] = f2bf(W1[k * NH + h]); return; }
        i -= PREP_W1T;
        if (i < PREP_W2T) { int e = i >> 8, h = i & 255; W2t[i] = f2bf(W2[h * NE + e]); return; }
        i -= PREP_W2T;
        if (i < PREP_WQ1T) { int hq = i >> 7, e = i & 127; Wq1at[i] = f2bf(Wq1[e * NH + hq]); return; }
        i -= PREP_WQ1T;
        if (i < PREP_PAD) { int eb = i / 48, mm = NN + (i % 48); encb[(size_t)eb * KP8 + kswz(mm)] = 0; }
        return;
    }
    if (blk < PREP_BLOCKS + MAX_BLOCKS) {
        const int bid = blk - PREP_BLOCKS;
        float m = 0.0f;
        for (size_t i = (size_t)bid * 256 + t; i < (size_t)NN * NN; i += (size_t)MAX_BLOCKS * 256)
            m = fmaxf(m, dm[i]);
        sh[t] = m; __syncthreads();
        for (int s = 128; s > 0; s >>= 1) {
            if (t < s) sh[t] = fmaxf(sh[t], sh[t + s]);
            __syncthreads();
        }
        if (t == 0) pmax[bid] = sh[0];
        return;
    }
    const int b = t >> 3, a = t & 7;
    float v = -1.0f;
    for (int j = 0; j < 3; ++j)
        if (fid[j] == a) v = (float)fa[j * NB + b] / ACTION_NORM;
    actions[t] = v;
}

// ---------------------------------------------------------------- merged: fused enc1+enc2 (blocks 0..999) + sim (1000..2999)
// enc12 block: 64 rows gm=blk*64 of r=(b*2000+m) space.
//   Phase 1: h1t[64][256] = relu(state_b @ W1t^T + b1) -> LDS (stride H1S)
//   Phase 2: enc[e=128][local m=64] = W2t @ h1t^T + b2 -> fp8 encb (PERM + kswz)
// sim block n: simb[n][*] fp8 (kswz), inv_rs[n]; dmax from pmax reduce.
__global__ __launch_bounds__(512) void k_sim_enc(
        const u16* __restrict__ state_b, const u16* __restrict__ W1t,
        const u16* __restrict__ W2t, u8* __restrict__ encb,
        const float* __restrict__ b1, const float* __restrict__ b2,
        const float* __restrict__ dm, const float* __restrict__ pmax,
        u8* __restrict__ simb, float* __restrict__ inv_rs) {
    __shared__ u16 stage[20 * 512];        // 20 KB staging
    __shared__ u16 h1t[64 * H1S];          // 33 KB h1 tile
    const int blk = blockIdx.x, tid = threadIdx.x;

    if (blk >= 1000) {
        // ---------------- sim part (512 threads)
        float* shf = (float*)stage;
        const int n = blk - 1000, t = tid;
        float m = fmaxf(pmax[t], pmax[t + 512]);
        shf[t] = m; __syncthreads();
        for (int s = 256; s > 0; s >>= 1) {
            if (t < s) shf[t] = fmaxf(shf[t], shf[t + s]);
            __syncthreads();
        }
        const float inv = 1.0f / shf[0];
        __syncthreads();
        float s = 0.0f;
        for (int mm = t * 2; mm < KP8; mm += 1024) {
            float e0 = 0.0f, e1 = 0.0f;
            if (mm < NN)     { e0 = expf(-dm[(size_t)n * NN + mm] * inv);     s += e0; }
            if (mm + 1 < NN) { e1 = expf(-dm[(size_t)n * NN + mm + 1] * inv); s += e1; }
            *(u16*)(simb + (size_t)n * KP8 + kswz(mm)) = f2fp8x2(e0, e1);
        }
        shf[t] = s; __syncthreads();
        for (int st = 256; st > 0; st >>= 1) {
            if (t < st) shf[t] += shf[t + st];
            __syncthreads();
        }
        if (t == 0) inv_rs[n] = 1.0f / shf[0];
        return;
    }

    // ---------------- enc12 part (8 waves)
    const int w = tid >> 6, l = tid & 63;
    const int lm = l & 15, lq = l >> 4;
    const int gm = blk * 64;

    // ---- phase 1: h1 tile (M=64, N=256, K=32). Chunks: 0-3 = A rows, 4-19 = W1t rows.
    {
#pragma unroll
        for (int i = 0; i < 3; ++i) {
            const int idx = w * 3 + i;
            if (idx < 20) {
                const u16* gp;
                if (idx < 4) gp = state_b + (size_t)(gm + idx * 16 + lm) * NRD + lq * 8;
                else         gp = W1t + (size_t)((idx - 4) * 16 + lm) * NRD + lq * 8;
                __builtin_amdgcn_global_load_lds((gptr_t)gp, (lptr_t)(stage + idx * 512), 16, 0, 0);
            }
        }
        __syncthreads();
        b16x8 af[4], bf[2];
#pragma unroll
        for (int i = 0; i < 4; ++i) af[i] = *(const b16x8*)(stage + i * 512 + l * 8);
#pragma unroll
        for (int j = 0; j < 2; ++j) bf[j] = *(const b16x8*)(stage + (4 + w * 2 + j) * 512 + l * 8);
        f32x4 acc1[4][2] = {};
#pragma unroll
        for (int i = 0; i < 4; ++i)
#pragma unroll
            for (int j = 0; j < 2; ++j)
                acc1[i][j] = __builtin_amdgcn_mfma_f32_16x16x32_bf16(af[i], bf[j], acc1[i][j], 0, 0, 0);
        // epilogue -> h1t LDS
#pragma unroll
        for (int i = 0; i < 4; ++i)
#pragma unroll
            for (int r = 0; r < 4; ++r) {
                const int row = i * 16 + lq * 4 + r;
#pragma unroll
                for (int j = 0; j < 2; ++j) {
                    const int col = w * 32 + j * 16 + lm;
                    h1t[row * H1S + col] = f2bf(fmaxf(acc1[i][j][r] + b1[col], 0.0f));
                }
            }
    }

    // ---- phase 2: enc tile (M=128 e, N=64 m, K=256), A=W2t staged, B=h1t LDS.
    const int wr = w & 3, wc = w >> 2;
    f32x4 acc2[2][2] = {};
    for (int k0 = 0; k0 < NH; k0 += 32) {
        __syncthreads();                    // h1t visible (1st iter) / stage free
        {
            const u16* gp = W2t + (size_t)(w * 16 + lm) * NH + k0 + lq * 8;
            __builtin_amdgcn_global_load_lds((gptr_t)gp, (lptr_t)(stage + w * 512), 16, 0, 0);
        }
        __syncthreads();
        b16x8 af2[2], bf2[2];
#pragma unroll
        for (int i = 0; i < 2; ++i)
            af2[i] = *(const b16x8*)(stage + (wr * 2 + i) * 512 + l * 8);
#pragma unroll
        for (int j = 0; j < 2; ++j)
            bf2[j] = *(const b16x8*)(h1t + (wc * 32 + j * 16 + lm) * H1S + k0 + lq * 8);
#pragma unroll
        for (int i = 0; i < 2; ++i)
#pragma unroll
            for (int j = 0; j < 2; ++j)
                acc2[i][j] = __builtin_amdgcn_mfma_f32_16x16x32_bf16(af2[i], bf2[j], acc2[i][j], 0, 0, 0);
    }
#pragma unroll
    for (int i = 0; i < 2; ++i)
#pragma unroll
        for (int r = 0; r < 4; ++r) {
            const int e = wr * 32 + i * 16 + lq * 4 + r;
            const float bias = b2[e];
#pragma unroll
            for (int j = 0; j < 2; ++j) {
                const int rg = gm + wc * 32 + j * 16 + lm;
                const unsigned bb = (unsigned)rg / 2000u;
                const unsigned mm = (unsigned)rg - bb * 2000u;
                encb[((size_t)bb * 128 + e) * KP8 + kswz((int)mm)] = f2fp8(acc2[i][j][r] + bias);
            }
        }
}

// ---------------------------------------------------------------- conv GEMM fp8, 128x128 tile, BK=64, 512 threads
// Xt[n][(b,e)] = inv_rs[n] * (simb8 @ encb8^T), bf16 out. kswz layout -> b128 frag reads.
__global__ __launch_bounds__(512) void k_conv(
        const u8* __restrict__ simb, const u8* __restrict__ encb,
        u16* __restrict__ Xt, const float* __restrict__ inv_rs) {
    __shared__ u8 lds[16 * 1024];           // 16 chunks x 1KB (A: 0-7, B: 8-15)
    const int tid = threadIdx.x;
    const int w = tid >> 6, l = tid & 63;   // 8 waves
    const int wr = w & 1, wc = w >> 1;      // wc in [0,4)
    const int bm = blockIdx.x * 128, bn = blockIdx.y * 128;
    const int lm = l & 15, lq = l >> 4;

    f32x4 acc[4][2] = {};

    for (int k0 = 0; k0 < KP8; k0 += 64) {
        __syncthreads();
#pragma unroll
        for (int i = 0; i < 2; ++i) {
            const int idx = w * 2 + i;
            const u8* gp;
            if (idx < 8) {
                int row = bm + idx * 16 + lm;
                row = row < NN ? row : NN - 1;
                gp = simb + (size_t)row * KP8 + k0 + lq * 16;
            } else {
                gp = encb + (size_t)(bn + (idx - 8) * 16 + lm) * KP8 + k0 + lq * 16;
            }
            __builtin_amdgcn_global_load_lds((gptr_t)gp, (lptr_t)(lds + idx * 1024), 16, 0, 0);
        }
        __syncthreads();
        const int fo = l * 16;              // lane-linear b128: conflict-free
        lx2 af[4], bf[2];
#pragma unroll
        for (int i = 0; i < 4; ++i)
            af[i] = *(const lx2*)(lds + (wr * 4 + i) * 1024 + fo);
#pragma unroll
        for (int j = 0; j < 2; ++j)
            bf[j] = *(const lx2*)(lds + (8 + wc * 2 + j) * 1024 + fo);
#pragma unroll
        for (int i = 0; i < 4; ++i)
#pragma unroll
            for (int j = 0; j < 2; ++j) {
                acc[i][j] = __builtin_amdgcn_mfma_f32_16x16x32_fp8_fp8(af[i][0], bf[j][0], acc[i][j], 0, 0, 0);
                acc[i][j] = __builtin_amdgcn_mfma_f32_16x16x32_fp8_fp8(af[i][1], bf[j][1], acc[i][j], 0, 0, 0);
            }
    }

#pragma unroll
    for (int i = 0; i < 4; ++i) {
#pragma unroll
        for (int r = 0; r < 4; ++r) {
            const int row = bm + wr * 64 + i * 16 + lq * 4 + r;
            if (row >= NN) continue;
            const float rsv = inv_rs[row];
#pragma unroll
            for (int j = 0; j < 2; ++j) {
                const int col = bn + wc * 32 + j * 16 + lm;
                Xt[(size_t)row * 4096 + col] = f2bf(acc[i][j][r] * rsv);
            }
        }
    }
}

// ---------------------------------------------------------------- y0 GEMM: Xt @ Wq1at^T + bq1, dual store bf16 + fp8
__global__ __launch_bounds__(256) void k_y0(
        const u16* __restrict__ A, const u16* __restrict__ Bt,
        u16* __restrict__ C, u8* __restrict__ Cf8,
        const float* __restrict__ bias) {
    __shared__ u16 lds[16 * 512];
    const int tid = threadIdx.x;
    const int w = tid >> 6, l = tid & 63;
    const int wr = w & 1, wc = w >> 1;
    const int bm = blockIdx.x * 128, bn = blockIdx.y * 128;
    const int lm = l & 15, lq = l >> 4;

    f32x4 acc[4][4] = {};

    for (int k0 = 0; k0 < NE; k0 += 32) {
        __syncthreads();
#pragma unroll
        for (int i = 0; i < 4; ++i) {
            const int idx = w * 4 + i;
            const u16* gp;
            if (idx < 8) {
                gp = A + (size_t)(bm + idx * 16 + lm) * NE + k0 + lq * 8;
            } else {
                gp = Bt + (size_t)(bn + (idx - 8) * 16 + lm) * NE + k0 + lq * 8;
            }
            __builtin_amdgcn_global_load_lds((gptr_t)gp, (lptr_t)(lds + idx * 512), 16, 0, 0);
        }
        __syncthreads();
        b16x8 af[4], bf[4];
#pragma unroll
        for (int i = 0; i < 4; ++i) {
            af[i] = *(const b16x8*)(lds + (wr * 4 + i) * 512 + l * 8);
            bf[i] = *(const b16x8*)(lds + (8 + wc * 4 + i) * 512 + l * 8);
        }
#pragma unroll
        for (int fr = 0; fr < 4; ++fr)
#pragma unroll
            for (int fc = 0; fc < 4; ++fc)
                acc[fr][fc] = __builtin_amdgcn_mfma_f32_16x16x32_bf16(af[fr], bf[fc], acc[fr][fc], 0, 0, 0);
    }

#pragma unroll
    for (int fr = 0; fr < 4; ++fr) {
#pragma unroll
        for (int r = 0; r < 4; ++r) {
            const int row = bm + wr * 64 + fr * 16 + lq * 4 + r;
#pragma unroll
            for (int fc = 0; fc < 4; ++fc) {
                const int col = bn + wc * 64 + fc * 16 + lm;
                const float v = acc[fr][fc][r] + bias[col];
                const size_t addr = (size_t)row * NH + col;
                C[addr] = f2bf(v);
                Cf8[addr] = f2fp8(v);
            }
        }
    }
}

// ---------------------------------------------------------------- per-agent kernel (round-9 proven)
// Phase A on fp8 y0 (quarter-wave per node); finalize reads bf16 y0w (one coalesced access).
__global__ __launch_bounds__(256) void k_agent(
        const u8* __restrict__ y0f8, const u16* __restrict__ y0,
        const float* __restrict__ Wq1, const float* __restrict__ Wq2,
        const float* __restrict__ bq2, float* actions,
        const float2* __restrict__ pin, float2* __restrict__ pout,
        float* __restrict__ out, int ag) {
    __shared__ float sh[256];
    __shared__ float s_sam;
    const int t = threadIdx.x;
    const int lane = t & 63, wave = t >> 6;
    const int wg = blockIdx.x * 4 + wave;
    const int b = wg & 31, ng = wg >> 5;        // ng in [0,128)
    const int hl = lane & 15, qtr = lane >> 4;

    float act[NA];
#pragma unroll
    for (int a = 0; a < NA; ++a) act[a] = actions[b * NA + a];
    if (ag > 0) {
        const float2 p0 = pin[b * NGP + lane];
        const float2 p1 = pin[b * NGP + 64 + lane];
        float se0 = p0.x + p1.x, sn0 = p0.y + p1.y;
#pragma unroll
        for (int m = 32; m > 0; m >>= 1) {
            se0 += __shfl_xor(se0, m); sn0 += __shfl_xor(sn0, m);
        }
        const float sam = fminf(fmaxf(sn0 / se0, 0.0f), 2000.0f);
        act[ag - 1] = sam * (1.0f / ACTION_NORM);
    }
    float ap16[16] = {};
#pragma unroll
    for (int a = 0; a < NA; ++a) {
        const float av = act[a];
        const float4* wq = (const float4*)(Wq1 + (size_t)(NE + a) * NH + hl * 16);
#pragma unroll
        for (int jj = 0; jj < 4; ++jj) {
            const float4 w4 = wq[jj];
            ap16[jj * 4 + 0] = fmaf(av, w4.x, ap16[jj * 4 + 0]);
            ap16[jj * 4 + 1] = fmaf(av, w4.y, ap16[jj * 4 + 1]);
            ap16[jj * 4 + 2] = fmaf(av, w4.z, ap16[jj * 4 + 2]);
            ap16[jj * 4 + 3] = fmaf(av, w4.w, ap16[jj * 4 + 3]);
        }
    }
    float w2v[16];
    {
        const float4* w2p = (const float4*)(Wq2 + hl * 16);
#pragma unroll
        for (int jj = 0; jj < 4; ++jj) {
            const float4 w4 = w2p[jj];
            w2v[jj * 4 + 0] = w4.x; w2v[jj * 4 + 1] = w4.y;
            w2v[jj * 4 + 2] = w4.z; w2v[jj * 4 + 3] = w4.w;
        }
    }

    float se = 0.0f, sn = 0.0f;
#pragma unroll
    for (int k = 0; k < 4; ++k) {
        const int p = ng + k * NGP;
        if (p >= NN / 4) break;
        const int n = 4 * p + qtr;
        const uint4 yv = *(const uint4*)(y0f8 + (((size_t)n * NB + b) << 8) + hl * 16);
        const unsigned dw[4] = {yv.x, yv.y, yv.z, yv.w};
        float q = 0.0f;
#pragma unroll
        for (int d = 0; d < 4; ++d) {
            const auto lo = __builtin_amdgcn_cvt_pk_f32_fp8(dw[d], false);
            const auto hi = __builtin_amdgcn_cvt_pk_f32_fp8(dw[d], true);
            q += fmaxf(lo[0] + ap16[d * 4 + 0], 0.f) * w2v[d * 4 + 0];
            q += fmaxf(lo[1] + ap16[d * 4 + 1], 0.f) * w2v[d * 4 + 1];
            q += fmaxf(hi[0] + ap16[d * 4 + 2], 0.f) * w2v[d * 4 + 2];
            q += fmaxf(hi[1] + ap16[d * 4 + 3], 0.f) * w2v[d * 4 + 3];
        }
#pragma unroll
        for (int off = 1; off < 16; off <<= 1) q += __shfl_xor(q, off);
        const float e = expf(fminf(q, 60.0f));
        se += e; sn += e * (float)n;
    }
    se += __shfl_xor(se, 16); sn += __shfl_xor(sn, 16);
    se += __shfl_xor(se, 32); sn += __shfl_xor(sn, 32);
    if (lane == 0) pout[b * NGP + ng] = make_float2(se, sn);

    if (ag > 0 && blockIdx.x < NB) {
        const int bb = blockIdx.x;
        if (wave == 0) {
            const float2 p0 = pin[bb * NGP + lane];
            const float2 p1 = pin[bb * NGP + 64 + lane];
            float a1 = p0.x + p1.x, a2 = p0.y + p1.y;
#pragma unroll
            for (int m = 32; m > 0; m >>= 1) {
                a1 += __shfl_xor(a1, m); a2 += __shfl_xor(a2, m);
            }
            if (lane == 0) s_sam = fminf(fmaxf(a2 / a1, 0.0f), 2000.0f);
        }
        __syncthreads();
        const float sam = s_sam;
        const float samn = sam * (1.0f / ACTION_NORM);
        float apt = 0.0f;
#pragma unroll
        for (int a = 0; a < NA; ++a) {
            const float av = (a == ag - 1) ? samn : actions[bb * NA + a];
            apt = fmaf(av, Wq1[(size_t)(NE + a) * NH + t], apt);
        }
        int nsel = (int)sam; if (nsel > NN - 1) nsel = NN - 1;
        const float yv = bf2f(y0[((size_t)nsel * NB + bb) * NH + t]);
        sh[t] = fmaxf(yv + apt, 0.0f) * Wq2[t];
        __syncthreads();
        for (int s = 128; s > 0; s >>= 1) {
            if (t < s) sh[t] += sh[t + s];
            __syncthreads();
        }
        if (t == 0) {
            out[bb * NA + (ag - 1)] = sh[0] + bq2[0];
            actions[bb * NA + (ag - 1)] = samn;
        }
    }
}

// ---------------------------------------------------------------- tail: finalize agent 7 + chosen
__global__ __launch_bounds__(256) void k_fin(
        const u16* __restrict__ y0, const float* __restrict__ Wq1,
        const float* __restrict__ Wq2, const float* __restrict__ bq2,
        const float* __restrict__ actions, const float2* __restrict__ pin,
        float* __restrict__ out) {
    __shared__ float sh[256];
    __shared__ float s_sam;
    const int bb = blockIdx.x, t = threadIdx.x;
    const int lane = t & 63, wave = t >> 6;
    if (wave == 0) {
        const float2 p0 = pin[bb * NGP + lane];
        const float2 p1 = pin[bb * NGP + 64 + lane];
        float a1 = p0.x + p1.x, a2 = p0.y + p1.y;
#pragma unroll
        for (int m = 32; m > 0; m >>= 1) {
            a1 += __shfl_xor(a1, m); a2 += __shfl_xor(a2, m);
        }
        if (lane == 0) s_sam = fminf(fmaxf(a2 / a1, 0.0f), 2000.0f);
    }
    __syncthreads();
    const float sam = s_sam;
    const float samn = sam * (1.0f / ACTION_NORM);
    float apt = 0.0f;
#pragma unroll
    for (int a = 0; a < NA; ++a) {
        const float av = (a == NA - 1) ? samn : actions[bb * NA + a];
        apt = fmaf(av, Wq1[(size_t)(NE + a) * NH + t], apt);
    }
    int nsel = (int)sam; if (nsel > NN - 1) nsel = NN - 1;
    const float yv = bf2f(y0[((size_t)nsel * NB + bb) * NH + t]);
    sh[t] = fmaxf(yv + apt, 0.0f) * Wq2[t];
    __syncthreads();
    for (int s = 128; s > 0; s >>= 1) {
        if (t < s) sh[t] += sh[t + s];
        __syncthreads();
    }
    if (t == 0) out[bb * NA + (NA - 1)] = sh[0] + bq2[0];
    if (t < NA) {
        const float av = (t == NA - 1) ? samn : actions[bb * NA + t];
        out[NB * NA + bb * NA + t] = (float)(int)(av * ACTION_NORM);
    }
}

// ---------------------------------------------------------------- launch
extern "C" void kernel_launch(void* const* d_in, const int* in_sizes, int n_in,
                              void* d_out, int out_size, void* d_ws, size_t ws_size,
                              hipStream_t stream) {
    const float* state = (const float*)d_in[0];
    const float* dm    = (const float*)d_in[1];
    const float* W1    = (const float*)d_in[2];
    const float* b1    = (const float*)d_in[3];
    const float* W2    = (const float*)d_in[4];
    const float* b2    = (const float*)d_in[5];
    const float* Wq1   = (const float*)d_in[6];
    const float* bq1   = (const float*)d_in[7];
    const float* Wq2   = (const float*)d_in[8];
    const float* bq2   = (const float*)d_in[9];
    const int* fa      = (const int*)d_in[10];
    const int* fid     = (const int*)d_in[11];
    float* out = (float*)d_out;

    char* p = (char*)d_ws;
    u8* simb       = (u8*)p;       p += (size_t)NN * KP8;           // 4.10 MB
    u8* encb       = (u8*)p;       p += (size_t)4096 * KP8;         // 8.39 MB
    float* inv_rs  = (float*)p;    p += 2048 * 4;
    float* pmax    = (float*)p;    p += 1024 * 4;
    float* actions = (float*)p;    p += 256 * 4;
    float2* part0  = (float2*)p;   p += (size_t)NB * NGP * 8;
    float2* part1  = (float2*)p;   p += (size_t)NB * NGP * 8;
    u16* state_b   = (u16*)p;      p += (size_t)2048000 * 2;
    u16* W1t       = (u16*)p;      p += 8192 * 2;
    u16* W2t       = (u16*)p;      p += 32768 * 2;
    u16* Wq1at     = (u16*)p;      p += 32768 * 2;
    u16* Xt        = (u16*)p;      p += (size_t)8192000 * 2;        // 16.4 MB
    u16* y0w       = (u16*)p;      p += (size_t)16384000 * 2;       // 32.8 MB
    u8* y0f8       = (u8*)p;       p += (size_t)16384000;           // 16.4 MB

    const int RTOT = NB * NN;  // 64000

    k_front<<<PREP_BLOCKS + MAX_BLOCKS + 1, 256, 0, stream>>>(
        state, W1, W2, Wq1, dm, fa, fid,
        state_b, W1t, W2t, Wq1at, encb, pmax, actions);
    // fused enc1+enc2 + sim
    k_sim_enc<<<3000, 512, 0, stream>>>(state_b, W1t, W2t, encb, b1, b2,
                                        dm, pmax, simb, inv_rs);
    // conv (fp8, kswz): Xt[n][(b,e)] = inv_rs[n] * (simb @ encb^T)
    k_conv<<<dim3(16, 32), 512, 0, stream>>>(simb, encb, Xt, inv_rs);
    // y0 = Xt @ Wq1[:128] + bq1, dual bf16 + fp8 store
    k_y0<<<dim3(RTOT / 128, NH / 128), 256, 0, stream>>>(Xt, Wq1at, y0w, y0f8, bq1);

    for (int ag = 0; ag < NA; ++ag) {
        const float2* pin  = (ag & 1) ? part0 : part1;
        float2*       pout = (ag & 1) ? part1 : part0;
        k_agent<<<1024, 256, 0, stream>>>(y0f8, y0w, Wq1, Wq2, bq2, actions,
                                          pin, pout, out, ag);
    }
    k_fin<<<NB, 256, 0, stream>>>(y0w, Wq1, Wq2, bq2, actions, part1, out);
}

// Round 12
// 273.028 us; speedup vs baseline: 1.1585x; 1.0407x over previous
//
#include <hip/hip_runtime.h>
#include <cstddef>

#define NB 32
#define NN 2000
#define NRD 32
#define NE 128
#define NH 256
#define NA 8
#define KP8 2048         // conv K padded (fp8, BK=64)
#define NGP 128          // node-quad groups per batch in k_agent
#define H1S 264          // h1 LDS tile stride (u16)
#define XTS 136          // X LDS tile stride (u16): 272B rows -> 2-way banks (free)
#define ACTION_NORM 2000.0f

typedef unsigned short u16;
typedef unsigned char u8;
typedef __bf16 b16x8 __attribute__((ext_vector_type(8)));
typedef float f32x4 __attribute__((ext_vector_type(4)));
typedef long lx2 __attribute__((ext_vector_type(2)));
typedef const __attribute__((address_space(1))) unsigned int* gptr_t;
typedef __attribute__((address_space(3))) unsigned int* lptr_t;

__device__ inline u16 f2bf(float x) {
    unsigned u = __float_as_uint(x);
    u += 0x7FFFu + ((u >> 16) & 1u);
    return (u16)(u >> 16);
}
__device__ inline float bf2f(u16 h) { return __uint_as_float((unsigned)h << 16); }
__device__ inline u8 f2fp8(float x) {
    return (u8)(__builtin_amdgcn_cvt_pk_fp8_f32(x, x, 0, false) & 0xFF);
}
__device__ inline u16 f2fp8x2(float a, float b) {
    return (u16)(__builtin_amdgcn_cvt_pk_fp8_f32(a, b, 0, false) & 0xFFFF);
}
__device__ inline float fp82f(u8 b) {
    return __builtin_amdgcn_cvt_pk_f32_fp8((unsigned)b, false)[0];
}
// fp8 K-swizzle: conv fragment reads become one lane-linear ds_read_b128 (conflict-free; R10 verified).
__device__ inline int kswz(int m) {
    return (m & ~63) + (((m >> 3) & 3) << 4) + (((m >> 5) & 1) << 3) + (m & 7);
}

// ---------------------------------------------------------------- front: prep + dm partial max + actions init
#define PREP_STATE (64000 * 32)
#define PREP_W1T   (256 * 32)
#define PREP_W2T   (128 * 256)
#define PREP_WQ1T  (256 * 128)
#define PREP_PAD   (4096 * 48)
#define PREP_TOT   (PREP_STATE + PREP_W1T + PREP_W2T + PREP_WQ1T + PREP_PAD)
#define PREP_BLOCKS (PREP_TOT / 256)       // 9056
#define MAX_BLOCKS 1024
__global__ __launch_bounds__(256) void k_front(
        const float* __restrict__ state, const float* __restrict__ W1,
        const float* __restrict__ W2, const float* __restrict__ Wq1,
        const float* __restrict__ dm, const int* __restrict__ fa,
        const int* __restrict__ fid,
        u16* __restrict__ state_b, u16* __restrict__ W1t,
        u16* __restrict__ W2t, u16* __restrict__ Wq1at,
        u8* __restrict__ encb, float* __restrict__ pmax,
        float* __restrict__ actions) {
    __shared__ float sh[256];
    const int blk = blockIdx.x, t = threadIdx.x;
    if (blk < PREP_BLOCKS) {
        int i = blk * 256 + t;
        if (i < PREP_STATE) { state_b[i] = f2bf(state[i]); return; }
        i -= PREP_STATE;
        if (i < PREP_W1T) { int h = i >> 5, k = i & 31; W1t[i] = f2bf(W1[k * NH + h]); return; }
        i -= PREP_W1T;
        if (i < PREP_W2T) { int e = i >> 8, h = i & 255; W2t[i] = f2bf(W2[h * NE + e]); return; }
        i -= PREP_W2T;
        if (i < PREP_WQ1T) { int hq = i >> 7, e = i & 127; Wq1at[i] = f2bf(Wq1[e * NH + hq]); return; }
        i -= PREP_WQ1T;
        if (i < PREP_PAD) { int eb = i / 48, mm = NN + (i % 48); encb[(size_t)eb * KP8 + kswz(mm)] = 0; }
        return;
    }
    if (blk < PREP_BLOCKS + MAX_BLOCKS) {
        const int bid = blk - PREP_BLOCKS;
        float m = 0.0f;
        for (size_t i = (size_t)bid * 256 + t; i < (size_t)NN * NN; i += (size_t)MAX_BLOCKS * 256)
            m = fmaxf(m, dm[i]);
        sh[t] = m; __syncthreads();
        for (int s = 128; s > 0; s >>= 1) {
            if (t < s) sh[t] = fmaxf(sh[t], sh[t + s]);
            __syncthreads();
        }
        if (t == 0) pmax[bid] = sh[0];
        return;
    }
    const int b = t >> 3, a = t & 7;
    float v = -1.0f;
    for (int j = 0; j < 3; ++j)
        if (fid[j] == a) v = (float)fa[j * NB + b] / ACTION_NORM;
    actions[t] = v;
}

// ---------------------------------------------------------------- merged: fused enc1+enc2 (blocks 0..999) + sim (1000..2999)
__global__ __launch_bounds__(512) void k_sim_enc(
        const u16* __restrict__ state_b, const u16* __restrict__ W1t,
        const u16* __restrict__ W2t, u8* __restrict__ encb,
        const float* __restrict__ b1, const float* __restrict__ b2,
        const float* __restrict__ dm, const float* __restrict__ pmax,
        u8* __restrict__ simb, float* __restrict__ inv_rs) {
    __shared__ u16 stage[20 * 512];        // 20 KB staging
    __shared__ u16 h1t[64 * H1S];          // 33 KB h1 tile
    const int blk = blockIdx.x, tid = threadIdx.x;

    if (blk >= 1000) {
        // ---------------- sim part (512 threads)
        float* shf = (float*)stage;
        const int n = blk - 1000, t = tid;
        float m = fmaxf(pmax[t], pmax[t + 512]);
        shf[t] = m; __syncthreads();
        for (int s = 256; s > 0; s >>= 1) {
            if (t < s) shf[t] = fmaxf(shf[t], shf[t + s]);
            __syncthreads();
        }
        const float inv = 1.0f / shf[0];
        __syncthreads();
        float s = 0.0f;
        for (int mm = t * 2; mm < KP8; mm += 1024) {
            float e0 = 0.0f, e1 = 0.0f;
            if (mm < NN)     { e0 = expf(-dm[(size_t)n * NN + mm] * inv);     s += e0; }
            if (mm + 1 < NN) { e1 = expf(-dm[(size_t)n * NN + mm + 1] * inv); s += e1; }
            *(u16*)(simb + (size_t)n * KP8 + kswz(mm)) = f2fp8x2(e0, e1);
        }
        shf[t] = s; __syncthreads();
        for (int st = 256; st > 0; st >>= 1) {
            if (t < st) shf[t] += shf[t + st];
            __syncthreads();
        }
        if (t == 0) inv_rs[n] = 1.0f / shf[0];
        return;
    }

    // ---------------- enc12 part (8 waves)
    const int w = tid >> 6, l = tid & 63;
    const int lm = l & 15, lq = l >> 4;
    const int gm = blk * 64;

    // ---- phase 1: h1 tile (M=64, N=256, K=32).
    {
#pragma unroll
        for (int i = 0; i < 3; ++i) {
            const int idx = w * 3 + i;
            if (idx < 20) {
                const u16* gp;
                if (idx < 4) gp = state_b + (size_t)(gm + idx * 16 + lm) * NRD + lq * 8;
                else         gp = W1t + (size_t)((idx - 4) * 16 + lm) * NRD + lq * 8;
                __builtin_amdgcn_global_load_lds((gptr_t)gp, (lptr_t)(stage + idx * 512), 16, 0, 0);
            }
        }
        __syncthreads();
        b16x8 af[4], bf[2];
#pragma unroll
        for (int i = 0; i < 4; ++i) af[i] = *(const b16x8*)(stage + i * 512 + l * 8);
#pragma unroll
        for (int j = 0; j < 2; ++j) bf[j] = *(const b16x8*)(stage + (4 + w * 2 + j) * 512 + l * 8);
        f32x4 acc1[4][2] = {};
#pragma unroll
        for (int i = 0; i < 4; ++i)
#pragma unroll
            for (int j = 0; j < 2; ++j)
                acc1[i][j] = __builtin_amdgcn_mfma_f32_16x16x32_bf16(af[i], bf[j], acc1[i][j], 0, 0, 0);
#pragma unroll
        for (int i = 0; i < 4; ++i)
#pragma unroll
            for (int r = 0; r < 4; ++r) {
                const int row = i * 16 + lq * 4 + r;
#pragma unroll
                for (int j = 0; j < 2; ++j) {
                    const int col = w * 32 + j * 16 + lm;
                    h1t[row * H1S + col] = f2bf(fmaxf(acc1[i][j][r] + b1[col], 0.0f));
                }
            }
    }

    // ---- phase 2: enc tile (M=128 e, N=64 m, K=256), A=W2t staged, B=h1t LDS.
    const int wr = w & 3, wc = w >> 2;
    f32x4 acc2[2][2] = {};
    for (int k0 = 0; k0 < NH; k0 += 32) {
        __syncthreads();
        {
            const u16* gp = W2t + (size_t)(w * 16 + lm) * NH + k0 + lq * 8;
            __builtin_amdgcn_global_load_lds((gptr_t)gp, (lptr_t)(stage + w * 512), 16, 0, 0);
        }
        __syncthreads();
        b16x8 af2[2], bf2[2];
#pragma unroll
        for (int i = 0; i < 2; ++i)
            af2[i] = *(const b16x8*)(stage + (wr * 2 + i) * 512 + l * 8);
#pragma unroll
        for (int j = 0; j < 2; ++j)
            bf2[j] = *(const b16x8*)(h1t + (wc * 32 + j * 16 + lm) * H1S + k0 + lq * 8);
#pragma unroll
        for (int i = 0; i < 2; ++i)
#pragma unroll
            for (int j = 0; j < 2; ++j)
                acc2[i][j] = __builtin_amdgcn_mfma_f32_16x16x32_bf16(af2[i], bf2[j], acc2[i][j], 0, 0, 0);
    }
#pragma unroll
    for (int i = 0; i < 2; ++i)
#pragma unroll
        for (int r = 0; r < 4; ++r) {
            const int e = wr * 32 + i * 16 + lq * 4 + r;
            const float bias = b2[e];
#pragma unroll
            for (int j = 0; j < 2; ++j) {
                const int rg = gm + wc * 32 + j * 16 + lm;
                const unsigned bb = (unsigned)rg / 2000u;
                const unsigned mm = (unsigned)rg - bb * 2000u;
                encb[((size_t)bb * 128 + e) * KP8 + kswz((int)mm)] = f2fp8(acc2[i][j][r] + bias);
            }
        }
}

// ---------------------------------------------------------------- fused conv + y0 (fp8 in, fp8 y0 out)
// grid (16, 32): block = (node-tile bm, batch bb). 512 threads, 8 waves.
// Phase 1: X[128n][128e] = inv_rs * (simb @ encb[bb]^T)  -> LDS xt (stride XTS)
// Phase 2: y0f8[(n*32+bb)][h] = fp8(xt @ Wq1at^T + bq1), wave w -> h in [w*32, w*32+32)
__global__ __launch_bounds__(512) void k_conv_y0(
        const u8* __restrict__ simb, const u8* __restrict__ encb,
        const u16* __restrict__ Wq1at, const float* __restrict__ inv_rs,
        const float* __restrict__ bq1, u8* __restrict__ y0f8) {
    __shared__ u8 lds[16 * 1024];           // 16 KB staging
    __shared__ u16 xt[128 * XTS];           // 34 KB X tile
    const int tid = threadIdx.x;
    const int w = tid >> 6, l = tid & 63;   // 8 waves
    const int wr = w & 1, wc = w >> 1;      // wc in [0,4)
    const int bm = blockIdx.x * 128;
    const int bb = blockIdx.y;
    const int lm = l & 15, lq = l >> 4;
    const u8* Bt = encb + (size_t)bb * 128 * KP8;

    f32x4 acc[4][2] = {};

    for (int k0 = 0; k0 < KP8; k0 += 64) {
        __syncthreads();
#pragma unroll
        for (int i = 0; i < 2; ++i) {
            const int idx = w * 2 + i;
            const u8* gp;
            if (idx < 8) {
                int row = bm + idx * 16 + lm;
                row = row < NN ? row : NN - 1;
                gp = simb + (size_t)row * KP8 + k0 + lq * 16;
            } else {
                gp = Bt + (size_t)((idx - 8) * 16 + lm) * KP8 + k0 + lq * 16;
            }
            __builtin_amdgcn_global_load_lds((gptr_t)gp, (lptr_t)(lds + idx * 1024), 16, 0, 0);
        }
        __syncthreads();
        const int fo = l * 16;              // lane-linear b128: conflict-free
        lx2 af[4], bf[2];
#pragma unroll
        for (int i = 0; i < 4; ++i)
            af[i] = *(const lx2*)(lds + (wr * 4 + i) * 1024 + fo);
#pragma unroll
        for (int j = 0; j < 2; ++j)
            bf[j] = *(const lx2*)(lds + (8 + wc * 2 + j) * 1024 + fo);
#pragma unroll
        for (int i = 0; i < 4; ++i)
#pragma unroll
            for (int j = 0; j < 2; ++j) {
                acc[i][j] = __builtin_amdgcn_mfma_f32_16x16x32_fp8_fp8(af[i][0], bf[j][0], acc[i][j], 0, 0, 0);
                acc[i][j] = __builtin_amdgcn_mfma_f32_16x16x32_fp8_fp8(af[i][1], bf[j][1], acc[i][j], 0, 0, 0);
            }
    }

    // ---- epilogue 1: scaled X tile -> LDS
    __syncthreads();
#pragma unroll
    for (int i = 0; i < 4; ++i) {
#pragma unroll
        for (int r = 0; r < 4; ++r) {
            const int row = wr * 64 + i * 16 + lq * 4 + r;
            const int gn = bm + row;
            const float rsv = inv_rs[gn < NN ? gn : NN - 1];
#pragma unroll
            for (int j = 0; j < 2; ++j) {
                const int col = wc * 32 + j * 16 + lm;
                xt[row * XTS + col] = f2bf(acc[i][j][r] * rsv);
            }
        }
    }
    __syncthreads();

    // ---- phase 2: y0 tile, two 64-row halves (acc reuse keeps VGPR low)
    for (int half = 0; half < 2; ++half) {
        f32x4 acc2[4][2] = {};
#pragma unroll
        for (int ks = 0; ks < 4; ++ks) {
            b16x8 bfw[2];
#pragma unroll
            for (int j = 0; j < 2; ++j)
                bfw[j] = *(const b16x8*)(Wq1at + (size_t)(w * 32 + j * 16 + lm) * NE + ks * 32 + lq * 8);
#pragma unroll
            for (int i = 0; i < 4; ++i) {
                const b16x8 afx = *(const b16x8*)(xt + (half * 64 + i * 16 + lm) * XTS + ks * 32 + lq * 8);
#pragma unroll
                for (int j = 0; j < 2; ++j)
                    acc2[i][j] = __builtin_amdgcn_mfma_f32_16x16x32_bf16(afx, bfw[j], acc2[i][j], 0, 0, 0);
            }
        }
#pragma unroll
        for (int i = 0; i < 4; ++i) {
#pragma unroll
            for (int r = 0; r < 4; ++r) {
                const int n = bm + half * 64 + i * 16 + lq * 4 + r;
                if (n >= NN) continue;
#pragma unroll
                for (int j = 0; j < 2; ++j) {
                    const int h = w * 32 + j * 16 + lm;
                    y0f8[((size_t)n * NB + bb) * NH + h] = f2fp8(acc2[i][j][r] + bq1[h]);
                }
            }
        }
    }
}

// ---------------------------------------------------------------- per-agent kernel
// Phase A on fp8 y0 (quarter-wave per node); finalize reads fp8 y0 row (coalesced).
__global__ __launch_bounds__(256) void k_agent(
        const u8* __restrict__ y0f8, const float* __restrict__ Wq1,
        const float* __restrict__ Wq2, const float* __restrict__ bq2,
        float* actions, const float2* __restrict__ pin, float2* __restrict__ pout,
        float* __restrict__ out, int ag) {
    __shared__ float sh[256];
    __shared__ float s_sam;
    const int t = threadIdx.x;
    const int lane = t & 63, wave = t >> 6;
    const int wg = blockIdx.x * 4 + wave;
    const int b = wg & 31, ng = wg >> 5;        // ng in [0,128)
    const int hl = lane & 15, qtr = lane >> 4;

    float act[NA];
#pragma unroll
    for (int a = 0; a < NA; ++a) act[a] = actions[b * NA + a];
    if (ag > 0) {
        const float2 p0 = pin[b * NGP + lane];
        const float2 p1 = pin[b * NGP + 64 + lane];
        float se0 = p0.x + p1.x, sn0 = p0.y + p1.y;
#pragma unroll
        for (int m = 32; m > 0; m >>= 1) {
            se0 += __shfl_xor(se0, m); sn0 += __shfl_xor(sn0, m);
        }
        const float sam = fminf(fmaxf(sn0 / se0, 0.0f), 2000.0f);
        act[ag - 1] = sam * (1.0f / ACTION_NORM);
    }
    float ap16[16] = {};
#pragma unroll
    for (int a = 0; a < NA; ++a) {
        const float av = act[a];
        const float4* wq = (const float4*)(Wq1 + (size_t)(NE + a) * NH + hl * 16);
#pragma unroll
        for (int jj = 0; jj < 4; ++jj) {
            const float4 w4 = wq[jj];
            ap16[jj * 4 + 0] = fmaf(av, w4.x, ap16[jj * 4 + 0]);
            ap16[jj * 4 + 1] = fmaf(av, w4.y, ap16[jj * 4 + 1]);
            ap16[jj * 4 + 2] = fmaf(av, w4.z, ap16[jj * 4 + 2]);
            ap16[jj * 4 + 3] = fmaf(av, w4.w, ap16[jj * 4 + 3]);
        }
    }
    float w2v[16];
    {
        const float4* w2p = (const float4*)(Wq2 + hl * 16);
#pragma unroll
        for (int jj = 0; jj < 4; ++jj) {
            const float4 w4 = w2p[jj];
            w2v[jj * 4 + 0] = w4.x; w2v[jj * 4 + 1] = w4.y;
            w2v[jj * 4 + 2] = w4.z; w2v[jj * 4 + 3] = w4.w;
        }
    }

    float se = 0.0f, sn = 0.0f;
#pragma unroll
    for (int k = 0; k < 4; ++k) {
        const int p = ng + k * NGP;
        if (p >= NN / 4) break;
        const int n = 4 * p + qtr;
        const uint4 yv = *(const uint4*)(y0f8 + (((size_t)n * NB + b) << 8) + hl * 16);
        const unsigned dw[4] = {yv.x, yv.y, yv.z, yv.w};
        float q = 0.0f;
#pragma unroll
        for (int d = 0; d < 4; ++d) {
            const auto lo = __builtin_amdgcn_cvt_pk_f32_fp8(dw[d], false);
            const auto hi = __builtin_amdgcn_cvt_pk_f32_fp8(dw[d], true);
            q += fmaxf(lo[0] + ap16[d * 4 + 0], 0.f) * w2v[d * 4 + 0];
            q += fmaxf(lo[1] + ap16[d * 4 + 1], 0.f) * w2v[d * 4 + 1];
            q += fmaxf(hi[0] + ap16[d * 4 + 2], 0.f) * w2v[d * 4 + 2];
            q += fmaxf(hi[1] + ap16[d * 4 + 3], 0.f) * w2v[d * 4 + 3];
        }
#pragma unroll
        for (int off = 1; off < 16; off <<= 1) q += __shfl_xor(q, off);
        const float e = expf(fminf(q, 60.0f));
        se += e; sn += e * (float)n;
    }
    se += __shfl_xor(se, 16); sn += __shfl_xor(sn, 16);
    se += __shfl_xor(se, 32); sn += __shfl_xor(sn, 32);
    if (lane == 0) pout[b * NGP + ng] = make_float2(se, sn);

    if (ag > 0 && blockIdx.x < NB) {
        const int bb = blockIdx.x;
        if (wave == 0) {
            const float2 p0 = pin[bb * NGP + lane];
            const float2 p1 = pin[bb * NGP + 64 + lane];
            float a1 = p0.x + p1.x, a2 = p0.y + p1.y;
#pragma unroll
            for (int m = 32; m > 0; m >>= 1) {
                a1 += __shfl_xor(a1, m); a2 += __shfl_xor(a2, m);
            }
            if (lane == 0) s_sam = fminf(fmaxf(a2 / a1, 0.0f), 2000.0f);
        }
        __syncthreads();
        const float sam = s_sam;
        const float samn = sam * (1.0f / ACTION_NORM);
        float apt = 0.0f;
#pragma unroll
        for (int a = 0; a < NA; ++a) {
            const float av = (a == ag - 1) ? samn : actions[bb * NA + a];
            apt = fmaf(av, Wq1[(size_t)(NE + a) * NH + t], apt);
        }
        int nsel = (int)sam; if (nsel > NN - 1) nsel = NN - 1;
        const float yv = fp82f(y0f8[((size_t)nsel * NB + bb) * NH + t]);
        sh[t] = fmaxf(yv + apt, 0.0f) * Wq2[t];
        __syncthreads();
        for (int s = 128; s > 0; s >>= 1) {
            if (t < s) sh[t] += sh[t + s];
            __syncthreads();
        }
        if (t == 0) {
            out[bb * NA + (ag - 1)] = sh[0] + bq2[0];
            actions[bb * NA + (ag - 1)] = samn;
        }
    }
}

// ---------------------------------------------------------------- tail: finalize agent 7 + chosen
__global__ __launch_bounds__(256) void k_fin(
        const u8* __restrict__ y0f8, const float* __restrict__ Wq1,
        const float* __restrict__ Wq2, const float* __restrict__ bq2,
        const float* __restrict__ actions, const float2* __restrict__ pin,
        float* __restrict__ out) {
    __shared__ float sh[256];
    __shared__ float s_sam;
    const int bb = blockIdx.x, t = threadIdx.x;
    const int lane = t & 63, wave = t >> 6;
    if (wave == 0) {
        const float2 p0 = pin[bb * NGP + lane];
        const float2 p1 = pin[bb * NGP + 64 + lane];
        float a1 = p0.x + p1.x, a2 = p0.y + p1.y;
#pragma unroll
        for (int m = 32; m > 0; m >>= 1) {
            a1 += __shfl_xor(a1, m); a2 += __shfl_xor(a2, m);
        }
        if (lane == 0) s_sam = fminf(fmaxf(a2 / a1, 0.0f), 2000.0f);
    }
    __syncthreads();
    const float sam = s_sam;
    const float samn = sam * (1.0f / ACTION_NORM);
    float apt = 0.0f;
#pragma unroll
    for (int a = 0; a < NA; ++a) {
        const float av = (a == NA - 1) ? samn : actions[bb * NA + a];
        apt = fmaf(av, Wq1[(size_t)(NE + a) * NH + t], apt);
    }
    int nsel = (int)sam; if (nsel > NN - 1) nsel = NN - 1;
    const float yv = fp82f(y0f8[((size_t)nsel * NB + bb) * NH + t]);
    sh[t] = fmaxf(yv + apt, 0.0f) * Wq2[t];
    __syncthreads();
    for (int s = 128; s > 0; s >>= 1) {
        if (t < s) sh[t] += sh[t + s];
        __syncthreads();
    }
    if (t == 0) out[bb * NA + (NA - 1)] = sh[0] + bq2[0];
    if (t < NA) {
        const float av = (t == NA - 1) ? samn : actions[bb * NA + t];
        out[NB * NA + bb * NA + t] = (float)(int)(av * ACTION_NORM);
    }
}

// ---------------------------------------------------------------- launch
extern "C" void kernel_launch(void* const* d_in, const int* in_sizes, int n_in,
                              void* d_out, int out_size, void* d_ws, size_t ws_size,
                              hipStream_t stream) {
    const float* state = (const float*)d_in[0];
    const float* dm    = (const float*)d_in[1];
    const float* W1    = (const float*)d_in[2];
    const float* b1    = (const float*)d_in[3];
    const float* W2    = (const float*)d_in[4];
    const float* b2    = (const float*)d_in[5];
    const float* Wq1   = (const float*)d_in[6];
    const float* bq1   = (const float*)d_in[7];
    const float* Wq2   = (const float*)d_in[8];
    const float* bq2   = (const float*)d_in[9];
    const int* fa      = (const int*)d_in[10];
    const int* fid     = (const int*)d_in[11];
    float* out = (float*)d_out;

    char* p = (char*)d_ws;
    u8* simb       = (u8*)p;       p += (size_t)NN * KP8;           // 4.10 MB
    u8* encb       = (u8*)p;       p += (size_t)4096 * KP8;         // 8.39 MB
    float* inv_rs  = (float*)p;    p += 2048 * 4;
    float* pmax    = (float*)p;    p += 1024 * 4;
    float* actions = (float*)p;    p += 256 * 4;
    float2* part0  = (float2*)p;   p += (size_t)NB * NGP * 8;
    float2* part1  = (float2*)p;   p += (size_t)NB * NGP * 8;
    u16* state_b   = (u16*)p;      p += (size_t)2048000 * 2;
    u16* W1t       = (u16*)p;      p += 8192 * 2;
    u16* W2t       = (u16*)p;      p += 32768 * 2;
    u16* Wq1at     = (u16*)p;      p += 32768 * 2;
    u8* y0f8       = (u8*)p;       p += (size_t)16384000;           // 16.4 MB

    k_front<<<PREP_BLOCKS + MAX_BLOCKS + 1, 256, 0, stream>>>(
        state, W1, W2, Wq1, dm, fa, fid,
        state_b, W1t, W2t, Wq1at, encb, pmax, actions);
    // fused enc1+enc2 + sim
    k_sim_enc<<<3000, 512, 0, stream>>>(state_b, W1t, W2t, encb, b1, b2,
                                        dm, pmax, simb, inv_rs);
    // fused conv + y0 (fp8 all the way)
    k_conv_y0<<<dim3(16, 32), 512, 0, stream>>>(simb, encb, Wq1at, inv_rs, bq1, y0f8);

    for (int ag = 0; ag < NA; ++ag) {
        const float2* pin  = (ag & 1) ? part0 : part1;
        float2*       pout = (ag & 1) ? part1 : part0;
        k_agent<<<1024, 256, 0, stream>>>(y0f8, Wq1, Wq2, bq2, actions,
                                          pin, pout, out, ag);
    }
    k_fin<<<NB, 256, 0, stream>>>(y0f8, Wq1, Wq2, bq2, actions, part1, out);
}

// Round 13
// 260.211 us; speedup vs baseline: 1.2156x; 1.0493x over previous
//
#include <hip/hip_runtime.h>
#include <cstddef>

#define NB 32
#define NN 2000
#define NRD 32
#define NE 128
#define NH 256
#define NA 8
#define KP8 2048         // conv K padded (fp8, BK=64)
#define NGP 128          // partial slots per batch
#define H1S 264          // h1 LDS tile stride (u16)
#define XT8S 136         // X fp8 LDS tile stride (bytes): 34 dw -> <=2-way banks
#define ACTION_NORM 2000.0f

typedef unsigned short u16;
typedef unsigned char u8;
typedef __bf16 b16x8 __attribute__((ext_vector_type(8)));
typedef float f32x4 __attribute__((ext_vector_type(4)));
typedef const __attribute__((address_space(1))) unsigned int* gptr_t;
typedef __attribute__((address_space(3))) unsigned int* lptr_t;

__device__ inline u16 f2bf(float x) {
    unsigned u = __float_as_uint(x);
    u += 0x7FFFu + ((u >> 16) & 1u);
    return (u16)(u >> 16);
}
__device__ inline float bf2f(u16 h) { return __uint_as_float((unsigned)h << 16); }
__device__ inline u8 f2fp8(float x) {
    return (u8)(__builtin_amdgcn_cvt_pk_fp8_f32(x, x, 0, false) & 0xFF);
}
__device__ inline u16 f2fp8x2(float a, float b) {
    return (u16)(__builtin_amdgcn_cvt_pk_fp8_f32(a, b, 0, false) & 0xFFFF);
}
__device__ inline float fp82f(u8 b) {
    return __builtin_amdgcn_cvt_pk_f32_fp8((unsigned)b, false)[0];
}
// fp8 K-swizzle for conv staging (R10-verified conflict-free b128 reads)
__device__ inline int kswz(int m) {
    return (m & ~63) + (((m >> 3) & 3) << 4) + (((m >> 5) & 1) << 3) + (m & 7);
}

// ---------------------------------------------------------------- front: prep + dm partial max + actions/ap0/part0 init
#define PREP_STATE (64000 * 32)
#define PREP_W1T   (256 * 32)
#define PREP_W2T   (128 * 256)
#define PREP_WQ1T  (256 * 128)
#define PREP_PAD   (4096 * 48)
#define PREP_TOT   (PREP_STATE + PREP_W1T + PREP_W2T + PREP_WQ1T + PREP_PAD)
#define PREP_BLOCKS (PREP_TOT / 256)       // 9056
#define MAX_BLOCKS 1024
__global__ __launch_bounds__(256) void k_front(
        const float* __restrict__ state, const float* __restrict__ W1,
        const float* __restrict__ W2, const float* __restrict__ Wq1,
        const float* __restrict__ dm, const int* __restrict__ fa,
        const int* __restrict__ fid,
        u16* __restrict__ state_b, u16* __restrict__ W1t,
        u16* __restrict__ W2t, u8* __restrict__ Wq1f8,
        u8* __restrict__ encb, float* __restrict__ pmax,
        float* __restrict__ actions, float* __restrict__ ap0,
        float2* __restrict__ part0) {
    __shared__ float sh[256];
    const int blk = blockIdx.x, t = threadIdx.x;
    if (blk < PREP_BLOCKS) {
        int i = blk * 256 + t;
        if (i < PREP_STATE) { state_b[i] = f2bf(state[i]); return; }
        i -= PREP_STATE;
        if (i < PREP_W1T) { int h = i >> 5, k = i & 31; W1t[i] = f2bf(W1[k * NH + h]); return; }
        i -= PREP_W1T;
        if (i < PREP_W2T) { int e = i >> 8, h = i & 255; W2t[i] = f2bf(W2[h * NE + e]); return; }
        i -= PREP_W2T;
        if (i < PREP_WQ1T) { int hq = i >> 7, e = i & 127; Wq1f8[i] = f2fp8(Wq1[e * NH + hq]); return; }
        i -= PREP_WQ1T;
        if (i < PREP_PAD) { int eb = i / 48, mm = NN + (i % 48); encb[(size_t)eb * KP8 + kswz(mm)] = 0; }
        return;
    }
    if (blk < PREP_BLOCKS + MAX_BLOCKS) {
        const int bid = blk - PREP_BLOCKS;
        float m = 0.0f;
        for (size_t i = (size_t)bid * 256 + t; i < (size_t)NN * NN; i += (size_t)MAX_BLOCKS * 256)
            m = fmaxf(m, dm[i]);
        sh[t] = m; __syncthreads();
        for (int s = 128; s > 0; s >>= 1) {
            if (t < s) sh[t] = fmaxf(sh[t], sh[t + s]);
            __syncthreads();
        }
        if (t == 0) pmax[bid] = sh[0];
        return;
    }
    // last block: actions init + agent-0 ap + zero part0
    const int b = t >> 3, a = t & 7;
    float v = -1.0f;
    for (int j = 0; j < 3; ++j)
        if (fid[j] == a) v = (float)fa[j * NB + b] / ACTION_NORM;
    actions[t] = v;
    sh[t] = v;
    __syncthreads();
    float wq[NA];
#pragma unroll
    for (int aa = 0; aa < NA; ++aa) wq[aa] = Wq1[(size_t)(NE + aa) * NH + t];
    for (int bb = 0; bb < NB; ++bb) {
        float s = 0.0f;
#pragma unroll
        for (int aa = 0; aa < NA; ++aa) s = fmaf(sh[bb * NA + aa], wq[aa], s);
        ap0[bb * NH + t] = s;
    }
    for (int i = t; i < NB * NGP; i += 256) part0[i] = make_float2(0.0f, 0.0f);
}

// ---------------------------------------------------------------- merged: fused enc1+enc2 (blocks 0..999) + sim (1000..2999)
__global__ __launch_bounds__(512) void k_sim_enc(
        const u16* __restrict__ state_b, const u16* __restrict__ W1t,
        const u16* __restrict__ W2t, u8* __restrict__ encb,
        const float* __restrict__ b1, const float* __restrict__ b2,
        const float* __restrict__ dm, const float* __restrict__ pmax,
        u8* __restrict__ simb, float* __restrict__ inv_rs) {
    __shared__ u16 stage[20 * 512];        // 20 KB staging
    __shared__ u16 h1t[64 * H1S];          // 33 KB h1 tile
    const int blk = blockIdx.x, tid = threadIdx.x;

    if (blk >= 1000) {
        // ---------------- sim part (512 threads)
        float* shf = (float*)stage;
        const int n = blk - 1000, t = tid;
        float m = fmaxf(pmax[t], pmax[t + 512]);
        shf[t] = m; __syncthreads();
        for (int s = 256; s > 0; s >>= 1) {
            if (t < s) shf[t] = fmaxf(shf[t], shf[t + s]);
            __syncthreads();
        }
        const float inv = 1.0f / shf[0];
        __syncthreads();
        float s = 0.0f;
        for (int mm = t * 2; mm < KP8; mm += 1024) {
            float e0 = 0.0f, e1 = 0.0f;
            if (mm < NN)     { e0 = expf(-dm[(size_t)n * NN + mm] * inv);     s += e0; }
            if (mm + 1 < NN) { e1 = expf(-dm[(size_t)n * NN + mm + 1] * inv); s += e1; }
            *(u16*)(simb + (size_t)n * KP8 + kswz(mm)) = f2fp8x2(e0, e1);
        }
        shf[t] = s; __syncthreads();
        for (int st = 256; st > 0; st >>= 1) {
            if (t < st) shf[t] += shf[t + st];
            __syncthreads();
        }
        if (t == 0) inv_rs[n] = 1.0f / shf[0];
        return;
    }

    // ---------------- enc12 part (8 waves)
    const int w = tid >> 6, l = tid & 63;
    const int lm = l & 15, lq = l >> 4;
    const int gm = blk * 64;

    // ---- phase 1: h1 tile (M=64, N=256, K=32).
    {
#pragma unroll
        for (int i = 0; i < 3; ++i) {
            const int idx = w * 3 + i;
            if (idx < 20) {
                const u16* gp;
                if (idx < 4) gp = state_b + (size_t)(gm + idx * 16 + lm) * NRD + lq * 8;
                else         gp = W1t + (size_t)((idx - 4) * 16 + lm) * NRD + lq * 8;
                __builtin_amdgcn_global_load_lds((gptr_t)gp, (lptr_t)(stage + idx * 512), 16, 0, 0);
            }
        }
        __syncthreads();
        b16x8 af[4], bf[2];
#pragma unroll
        for (int i = 0; i < 4; ++i) af[i] = *(const b16x8*)(stage + i * 512 + l * 8);
#pragma unroll
        for (int j = 0; j < 2; ++j) bf[j] = *(const b16x8*)(stage + (4 + w * 2 + j) * 512 + l * 8);
        f32x4 acc1[4][2] = {};
#pragma unroll
        for (int i = 0; i < 4; ++i)
#pragma unroll
            for (int j = 0; j < 2; ++j)
                acc1[i][j] = __builtin_amdgcn_mfma_f32_16x16x32_bf16(af[i], bf[j], acc1[i][j], 0, 0, 0);
#pragma unroll
        for (int i = 0; i < 4; ++i)
#pragma unroll
            for (int r = 0; r < 4; ++r) {
                const int row = i * 16 + lq * 4 + r;
#pragma unroll
                for (int j = 0; j < 2; ++j) {
                    const int col = w * 32 + j * 16 + lm;
                    h1t[row * H1S + col] = f2bf(fmaxf(acc1[i][j][r] + b1[col], 0.0f));
                }
            }
    }

    // ---- phase 2: enc tile (M=128 e, N=64 m, K=256), A=W2t staged, B=h1t LDS.
    const int wr = w & 3, wc = w >> 2;
    f32x4 acc2[2][2] = {};
    for (int k0 = 0; k0 < NH; k0 += 32) {
        __syncthreads();
        {
            const u16* gp = W2t + (size_t)(w * 16 + lm) * NH + k0 + lq * 8;
            __builtin_amdgcn_global_load_lds((gptr_t)gp, (lptr_t)(stage + w * 512), 16, 0, 0);
        }
        __syncthreads();
        b16x8 af2[2], bf2[2];
#pragma unroll
        for (int i = 0; i < 2; ++i)
            af2[i] = *(const b16x8*)(stage + (wr * 2 + i) * 512 + l * 8);
#pragma unroll
        for (int j = 0; j < 2; ++j)
            bf2[j] = *(const b16x8*)(h1t + (wc * 32 + j * 16 + lm) * H1S + k0 + lq * 8);
#pragma unroll
        for (int i = 0; i < 2; ++i)
#pragma unroll
            for (int j = 0; j < 2; ++j)
                acc2[i][j] = __builtin_amdgcn_mfma_f32_16x16x32_bf16(af2[i], bf2[j], acc2[i][j], 0, 0, 0);
    }
#pragma unroll
    for (int i = 0; i < 2; ++i)
#pragma unroll
        for (int r = 0; r < 4; ++r) {
            const int e = wr * 32 + i * 16 + lq * 4 + r;
            const float bias = b2[e];
#pragma unroll
            for (int j = 0; j < 2; ++j) {
                const int rg = gm + wc * 32 + j * 16 + lm;
                const unsigned bb = (unsigned)rg / 2000u;
                const unsigned mm = (unsigned)rg - bb * 2000u;
                encb[((size_t)bb * 128 + e) * KP8 + kswz((int)mm)] = f2fp8(acc2[i][j][r] + bias);
            }
        }
}

// ---------------------------------------------------------------- fused conv + y0 + agent-0 softmax partials
// grid (16, 32): block = (node-tile bm, batch bb). 512 threads, 8 waves.
// Phase 1: X[128n][128e] = inv_rs * (simb @ encb[bb]^T)  -> LDS xt8 (fp8, stride XT8S)
// Phase 2: y0 = xt8 @ Wq1f8^T + bq1 -> fp8 y0f8 (fp8 MFMA, K=128)
// Phase 3: agent-0 q(n) from fp32 acc2 + ap0 -> (se,sn) partial into part0[bb*NGP + tile]
__global__ __launch_bounds__(512) void k_conv_y0(
        const u8* __restrict__ simb, const u8* __restrict__ encb,
        const u8* __restrict__ Wq1f8, const float* __restrict__ inv_rs,
        const float* __restrict__ bq1, const float* __restrict__ ap0,
        const float* __restrict__ Wq2, u8* __restrict__ y0f8,
        float2* __restrict__ part0) {
    __shared__ u8 lds[16 * 1024];           // 16 KB staging
    __shared__ u8 xt8[128 * XT8S];          // 17 KB X tile (fp8)
    __shared__ float qsum[64 * 8];          // 2 KB per-row wave partials
    const int tid = threadIdx.x;
    const int w = tid >> 6, l = tid & 63;   // 8 waves
    const int wr = w & 1, wc = w >> 1;      // wc in [0,4)
    const int bm = blockIdx.x * 128;
    const int bb = blockIdx.y;
    const int lm = l & 15, lq = l >> 4;
    const u8* Bt = encb + (size_t)bb * 128 * KP8;

    f32x4 acc[4][2] = {};

    for (int k0 = 0; k0 < KP8; k0 += 64) {
        __syncthreads();
#pragma unroll
        for (int i = 0; i < 2; ++i) {
            const int idx = w * 2 + i;
            const u8* gp;
            if (idx < 8) {
                int row = bm + idx * 16 + lm;
                row = row < NN ? row : NN - 1;
                gp = simb + (size_t)row * KP8 + k0 + lq * 16;
            } else {
                gp = Bt + (size_t)((idx - 8) * 16 + lm) * KP8 + k0 + lq * 16;
            }
            __builtin_amdgcn_global_load_lds((gptr_t)gp, (lptr_t)(lds + idx * 1024), 16, 0, 0);
        }
        __syncthreads();
        const int fo = l * 16;              // lane-linear b128: conflict-free
        typedef long lx2 __attribute__((ext_vector_type(2)));
        lx2 af[4], bf[2];
#pragma unroll
        for (int i = 0; i < 4; ++i)
            af[i] = *(const lx2*)(lds + (wr * 4 + i) * 1024 + fo);
#pragma unroll
        for (int j = 0; j < 2; ++j)
            bf[j] = *(const lx2*)(lds + (8 + wc * 2 + j) * 1024 + fo);
#pragma unroll
        for (int i = 0; i < 4; ++i)
#pragma unroll
            for (int j = 0; j < 2; ++j) {
                acc[i][j] = __builtin_amdgcn_mfma_f32_16x16x32_fp8_fp8(af[i][0], bf[j][0], acc[i][j], 0, 0, 0);
                acc[i][j] = __builtin_amdgcn_mfma_f32_16x16x32_fp8_fp8(af[i][1], bf[j][1], acc[i][j], 0, 0, 0);
            }
    }

    // ---- epilogue 1: scaled X tile -> fp8 LDS
    __syncthreads();
#pragma unroll
    for (int i = 0; i < 4; ++i) {
#pragma unroll
        for (int r = 0; r < 4; ++r) {
            const int row = wr * 64 + i * 16 + lq * 4 + r;
            const int gn = bm + row;
            const float rsv = inv_rs[gn < NN ? gn : NN - 1];
#pragma unroll
            for (int j = 0; j < 2; ++j) {
                const int col = wc * 32 + j * 16 + lm;
                xt8[row * XT8S + col] = f2fp8(acc[i][j][r] * rsv);
            }
        }
    }
    __syncthreads();

    // ---- phase 2+3: y0 (fp8 MFMA) + agent-0 q partials
    const int h0 = w * 32;
    float bq1v[2], apv[2], w2vv[2];
#pragma unroll
    for (int j = 0; j < 2; ++j) {
        const int h = h0 + j * 16 + lm;
        bq1v[j] = bq1[h];
        apv[j] = ap0[bb * NH + h];
        w2vv[j] = Wq2[h];
    }
    float se_tot = 0.0f, sn_tot = 0.0f;

    for (int half = 0; half < 2; ++half) {
        f32x4 acc2[4][2] = {};
#pragma unroll
        for (int ks = 0; ks < 4; ++ks) {
            long bfw[2];
#pragma unroll
            for (int j = 0; j < 2; ++j)
                bfw[j] = *(const long*)(Wq1f8 + (size_t)(h0 + j * 16 + lm) * NE + ks * 32 + lq * 8);
#pragma unroll
            for (int i = 0; i < 4; ++i) {
                const long afx = *(const long*)(xt8 + (half * 64 + i * 16 + lm) * XT8S + ks * 32 + lq * 8);
#pragma unroll
                for (int j = 0; j < 2; ++j)
                    acc2[i][j] = __builtin_amdgcn_mfma_f32_16x16x32_fp8_fp8(afx, bfw[j], acc2[i][j], 0, 0, 0);
            }
        }
#pragma unroll
        for (int i = 0; i < 4; ++i) {
#pragma unroll
            for (int r = 0; r < 4; ++r) {
                const int rl = i * 16 + lq * 4 + r;
                const int n = bm + half * 64 + rl;
                float q = 0.0f;
#pragma unroll
                for (int j = 0; j < 2; ++j) {
                    const float v = acc2[i][j][r] + bq1v[j];
                    if (n < NN) y0f8[((size_t)n * NB + bb) * NH + h0 + j * 16 + lm] = f2fp8(v);
                    q += fmaxf(v + apv[j], 0.0f) * w2vv[j];
                }
#pragma unroll
                for (int off = 1; off < 16; off <<= 1) q += __shfl_xor(q, off);
                if (lm == 0) qsum[rl * 8 + w] = q;
            }
        }
        __syncthreads();
        if (tid < 64) {
            const int n = bm + half * 64 + tid;
            float q = 0.0f;
#pragma unroll
            for (int wv = 0; wv < 8; ++wv) q += qsum[tid * 8 + wv];
            float e = (n < NN) ? expf(fminf(q, 60.0f)) : 0.0f;
            float sne = e * (float)n;
#pragma unroll
            for (int off = 32; off > 0; off >>= 1) {
                e += __shfl_xor(e, off); sne += __shfl_xor(sne, off);
            }
            if (tid == 0) { se_tot += e; sn_tot += sne; }
        }
        __syncthreads();
    }
    if (tid == 0) part0[bb * NGP + blockIdx.x] = make_float2(se_tot, sn_tot);
}

// ---------------------------------------------------------------- per-agent kernel (ag = 1..7)
__global__ __launch_bounds__(256) void k_agent(
        const u8* __restrict__ y0f8, const float* __restrict__ Wq1,
        const float* __restrict__ Wq2, const float* __restrict__ bq2,
        float* actions, const float2* __restrict__ pin, float2* __restrict__ pout,
        float* __restrict__ out, int ag) {
    __shared__ float sh[256];
    __shared__ float s_sam;
    const int t = threadIdx.x;
    const int lane = t & 63, wave = t >> 6;
    const int wg = blockIdx.x * 4 + wave;
    const int b = wg & 31, ng = wg >> 5;        // ng in [0,128)
    const int hl = lane & 15, qtr = lane >> 4;

    float act[NA];
#pragma unroll
    for (int a = 0; a < NA; ++a) act[a] = actions[b * NA + a];
    {
        const float2 p0 = pin[b * NGP + lane];
        const float2 p1 = pin[b * NGP + 64 + lane];
        float se0 = p0.x + p1.x, sn0 = p0.y + p1.y;
#pragma unroll
        for (int m = 32; m > 0; m >>= 1) {
            se0 += __shfl_xor(se0, m); sn0 += __shfl_xor(sn0, m);
        }
        const float sam = fminf(fmaxf(sn0 / se0, 0.0f), 2000.0f);
        act[ag - 1] = sam * (1.0f / ACTION_NORM);
    }
    float ap16[16] = {};
#pragma unroll
    for (int a = 0; a < NA; ++a) {
        const float av = act[a];
        const float4* wq = (const float4*)(Wq1 + (size_t)(NE + a) * NH + hl * 16);
#pragma unroll
        for (int jj = 0; jj < 4; ++jj) {
            const float4 w4 = wq[jj];
            ap16[jj * 4 + 0] = fmaf(av, w4.x, ap16[jj * 4 + 0]);
            ap16[jj * 4 + 1] = fmaf(av, w4.y, ap16[jj * 4 + 1]);
            ap16[jj * 4 + 2] = fmaf(av, w4.z, ap16[jj * 4 + 2]);
            ap16[jj * 4 + 3] = fmaf(av, w4.w, ap16[jj * 4 + 3]);
        }
    }
    float w2v[16];
    {
        const float4* w2p = (const float4*)(Wq2 + hl * 16);
#pragma unroll
        for (int jj = 0; jj < 4; ++jj) {
            const float4 w4 = w2p[jj];
            w2v[jj * 4 + 0] = w4.x; w2v[jj * 4 + 1] = w4.y;
            w2v[jj * 4 + 2] = w4.z; w2v[jj * 4 + 3] = w4.w;
        }
    }

    float se = 0.0f, sn = 0.0f;
#pragma unroll
    for (int k = 0; k < 4; ++k) {
        const int p = ng + k * NGP;
        if (p >= NN / 4) break;
        const int n = 4 * p + qtr;
        const uint4 yv = *(const uint4*)(y0f8 + (((size_t)n * NB + b) << 8) + hl * 16);
        const unsigned dw[4] = {yv.x, yv.y, yv.z, yv.w};
        float q = 0.0f;
#pragma unroll
        for (int d = 0; d < 4; ++d) {
            const auto lo = __builtin_amdgcn_cvt_pk_f32_fp8(dw[d], false);
            const auto hi = __builtin_amdgcn_cvt_pk_f32_fp8(dw[d], true);
            q += fmaxf(lo[0] + ap16[d * 4 + 0], 0.f) * w2v[d * 4 + 0];
            q += fmaxf(lo[1] + ap16[d * 4 + 1], 0.f) * w2v[d * 4 + 1];
            q += fmaxf(hi[0] + ap16[d * 4 + 2], 0.f) * w2v[d * 4 + 2];
            q += fmaxf(hi[1] + ap16[d * 4 + 3], 0.f) * w2v[d * 4 + 3];
        }
#pragma unroll
        for (int off = 1; off < 16; off <<= 1) q += __shfl_xor(q, off);
        const float e = expf(fminf(q, 60.0f));
        se += e; sn += e * (float)n;
    }
    se += __shfl_xor(se, 16); sn += __shfl_xor(sn, 16);
    se += __shfl_xor(se, 32); sn += __shfl_xor(sn, 32);
    if (lane == 0) pout[b * NGP + ng] = make_float2(se, sn);

    if (blockIdx.x < NB) {
        const int bb = blockIdx.x;
        if (wave == 0) {
            const float2 p0 = pin[bb * NGP + lane];
            const float2 p1 = pin[bb * NGP + 64 + lane];
            float a1 = p0.x + p1.x, a2 = p0.y + p1.y;
#pragma unroll
            for (int m = 32; m > 0; m >>= 1) {
                a1 += __shfl_xor(a1, m); a2 += __shfl_xor(a2, m);
            }
            if (lane == 0) s_sam = fminf(fmaxf(a2 / a1, 0.0f), 2000.0f);
        }
        __syncthreads();
        const float sam = s_sam;
        const float samn = sam * (1.0f / ACTION_NORM);
        float apt = 0.0f;
#pragma unroll
        for (int a = 0; a < NA; ++a) {
            const float av = (a == ag - 1) ? samn : actions[bb * NA + a];
            apt = fmaf(av, Wq1[(size_t)(NE + a) * NH + t], apt);
        }
        int nsel = (int)sam; if (nsel > NN - 1) nsel = NN - 1;
        const float yv = fp82f(y0f8[((size_t)nsel * NB + bb) * NH + t]);
        sh[t] = fmaxf(yv + apt, 0.0f) * Wq2[t];
        __syncthreads();
        for (int s = 128; s > 0; s >>= 1) {
            if (t < s) sh[t] += sh[t + s];
            __syncthreads();
        }
        if (t == 0) {
            out[bb * NA + (ag - 1)] = sh[0] + bq2[0];
            actions[bb * NA + (ag - 1)] = samn;
        }
    }
}

// ---------------------------------------------------------------- tail: finalize agent 7 + chosen
__global__ __launch_bounds__(256) void k_fin(
        const u8* __restrict__ y0f8, const float* __restrict__ Wq1,
        const float* __restrict__ Wq2, const float* __restrict__ bq2,
        const float* __restrict__ actions, const float2* __restrict__ pin,
        float* __restrict__ out) {
    __shared__ float sh[256];
    __shared__ float s_sam;
    const int bb = blockIdx.x, t = threadIdx.x;
    const int lane = t & 63, wave = t >> 6;
    if (wave == 0) {
        const float2 p0 = pin[bb * NGP + lane];
        const float2 p1 = pin[bb * NGP + 64 + lane];
        float a1 = p0.x + p1.x, a2 = p0.y + p1.y;
#pragma unroll
        for (int m = 32; m > 0; m >>= 1) {
            a1 += __shfl_xor(a1, m); a2 += __shfl_xor(a2, m);
        }
        if (lane == 0) s_sam = fminf(fmaxf(a2 / a1, 0.0f), 2000.0f);
    }
    __syncthreads();
    const float sam = s_sam;
    const float samn = sam * (1.0f / ACTION_NORM);
    float apt = 0.0f;
#pragma unroll
    for (int a = 0; a < NA; ++a) {
        const float av = (a == NA - 1) ? samn : actions[bb * NA + a];
        apt = fmaf(av, Wq1[(size_t)(NE + a) * NH + t], apt);
    }
    int nsel = (int)sam; if (nsel > NN - 1) nsel = NN - 1;
    const float yv = fp82f(y0f8[((size_t)nsel * NB + bb) * NH + t]);
    sh[t] = fmaxf(yv + apt, 0.0f) * Wq2[t];
    __syncthreads();
    for (int s = 128; s > 0; s >>= 1) {
        if (t < s) sh[t] += sh[t + s];
        __syncthreads();
    }
    if (t == 0) out[bb * NA + (NA - 1)] = sh[0] + bq2[0];
    if (t < NA) {
        const float av = (t == NA - 1) ? samn : actions[bb * NA + t];
        out[NB * NA + bb * NA + t] = (float)(int)(av * ACTION_NORM);
    }
}

// ---------------------------------------------------------------- launch
extern "C" void kernel_launch(void* const* d_in, const int* in_sizes, int n_in,
                              void* d_out, int out_size, void* d_ws, size_t ws_size,
                              hipStream_t stream) {
    const float* state = (const float*)d_in[0];
    const float* dm    = (const float*)d_in[1];
    const float* W1    = (const float*)d_in[2];
    const float* b1    = (const float*)d_in[3];
    const float* W2    = (const float*)d_in[4];
    const float* b2    = (const float*)d_in[5];
    const float* Wq1   = (const float*)d_in[6];
    const float* bq1   = (const float*)d_in[7];
    const float* Wq2   = (const float*)d_in[8];
    const float* bq2   = (const float*)d_in[9];
    const int* fa      = (const int*)d_in[10];
    const int* fid     = (const int*)d_in[11];
    float* out = (float*)d_out;

    char* p = (char*)d_ws;
    u8* simb       = (u8*)p;       p += (size_t)NN * KP8;           // 4.10 MB
    u8* encb       = (u8*)p;       p += (size_t)4096 * KP8;         // 8.39 MB
    float* inv_rs  = (float*)p;    p += 2048 * 4;
    float* pmax    = (float*)p;    p += 1024 * 4;
    float* actions = (float*)p;    p += 256 * 4;
    float* ap0     = (float*)p;    p += 8192 * 4;
    float2* part0  = (float2*)p;   p += (size_t)NB * NGP * 8;
    float2* part1  = (float2*)p;   p += (size_t)NB * NGP * 8;
    u16* state_b   = (u16*)p;      p += (size_t)2048000 * 2;
    u16* W1t       = (u16*)p;      p += 8192 * 2;
    u16* W2t       = (u16*)p;      p += 32768 * 2;
    u8* Wq1f8      = (u8*)p;       p += 32768;
    u8* y0f8       = (u8*)p;       p += (size_t)16384000;           // 16.4 MB

    k_front<<<PREP_BLOCKS + MAX_BLOCKS + 1, 256, 0, stream>>>(
        state, W1, W2, Wq1, dm, fa, fid,
        state_b, W1t, W2t, Wq1f8, encb, pmax, actions, ap0, part0);
    // fused enc1+enc2 + sim
    k_sim_enc<<<3000, 512, 0, stream>>>(state_b, W1t, W2t, encb, b1, b2,
                                        dm, pmax, simb, inv_rs);
    // fused conv + y0 + agent-0 partials
    k_conv_y0<<<dim3(16, 32), 512, 0, stream>>>(simb, encb, Wq1f8, inv_rs, bq1,
                                                ap0, Wq2, y0f8, part0);
    // agents 1..7 (agent 0's partials came from k_conv_y0 into part0)
    for (int ag = 1; ag < NA; ++ag) {
        const float2* pin  = (ag & 1) ? part0 : part1;
        float2*       pout = (ag & 1) ? part1 : part0;
        k_agent<<<1024, 256, 0, stream>>>(y0f8, Wq1, Wq2, bq2, actions,
                                          pin, pout, out, ag);
    }
    // finalize agent 7 (+ chosen); ag=7 wrote part1
    k_fin<<<NB, 256, 0, stream>>>(y0f8, Wq1, Wq2, bq2, actions, part1, out);
}